// Round 6
// baseline (1307.218 us; speedup 1.0000x reference)
//
#include <hip/hip_runtime.h>
#include <hip/hip_bf16.h>
#include <math.h>

// Problem constants (fixed by reference)
#define D_MODEL   768
#define D_STATE   16
#define D_CONV    4
#define D_INNER   1536
#define DT_RANK   48
#define BATCH     4
#define SEQ_LEN   2048
#define BL        (BATCH * SEQ_LEN)        // 8192 rows
#define NCHUNK    32
#define CHUNK     (SEQ_LEN / NCHUNK)       // 64

typedef __bf16 bf16x8 __attribute__((ext_vector_type(8)));
typedef float  f32x4  __attribute__((ext_vector_type(4)));

__device__ __forceinline__ void async_copy16(const void* g, void* l) {
    __builtin_amdgcn_global_load_lds(
        (const __attribute__((address_space(1))) void*)g,
        (__attribute__((address_space(3))) void*)l,
        16, 0, 0);
}

// ===========================================================================
// R16 step-1 kernel: 256x256 tile, 8 waves, SINGLE-buffered 64 KB LDS,
// plain 2-barrier K-loop (structure clone of the proven R10/gemm_f body,
// scaled up).  Rationale: R13-R15 proved intra-block pipelining is worth
// ~0 at this shape (41% MfmaUtil across all variants), while 128 KB LDS
// cost co-residency: 1 block/CU -> 384 blocks run as 256+128 rounds (half
// the machine idle in round 2, Occupancy 15.5%).  64 KB LDS -> 2 blocks/CU
// co-resident -> one round, all CUs busy, barrier drain of one block hides
// under the other block's 96-MFMA tile (m114 cross-block overlap — the
// mechanism that made R10's 3-block/CU 128² work).
// Read/write lane mappings identical to R14/R15 (harness-verified).
// __launch_bounds__(512,4) caps VGPR at 128 (R14 measured 112).
// ===========================================================================

template<int IH, int JH>
__device__ __forceinline__ void quad24(f32x4 (&acc)[2][4][2][2],
                                       const bf16x8 (&aH)[4], const bf16x8 (&aL)[4],
                                       const bf16x8 (&bH)[2], const bf16x8 (&bL)[2])
{
    #pragma unroll
    for (int i = 0; i < 4; ++i)
        #pragma unroll
        for (int j = 0; j < 2; ++j) {
            acc[IH][i][JH][j] = __builtin_amdgcn_mfma_f32_16x16x32_bf16(aH[i], bH[j], acc[IH][i][JH][j], 0, 0, 0);
            acc[IH][i][JH][j] = __builtin_amdgcn_mfma_f32_16x16x32_bf16(aH[i], bL[j], acc[IH][i][JH][j], 0, 0, 0);
            acc[IH][i][JH][j] = __builtin_amdgcn_mfma_f32_16x16x32_bf16(aL[i], bH[j], acc[IH][i][JH][j], 0, 0, 0);
        }
}

__global__ __launch_bounds__(512, 4)
void gemm256(const __bf16* __restrict__ A, const __bf16* __restrict__ B,
             float* __restrict__ C, int K, int ldc)
{
    __shared__ __bf16 Asl[256 * 64];    // 32 KB
    __shared__ __bf16 Bsl[256 * 64];    // 32 KB

    const int tid  = threadIdx.x;
    const int lane = tid & 63;
    const int w    = tid >> 6;          // 0..7
    const int aw   = (w >> 2) * 64;     // A sub-slice within each 128-row half
    const int bw   = (w & 3) * 32;      // B sub-slice within each 128-row half

    const int bm = blockIdx.y * 256;
    const int bn = blockIdx.x * 256;

    const long lda = 2L * K;
    const long ldb = 2L * K;

    f32x4 acc[2][4][2][2];
    #pragma unroll
    for (int a = 0; a < 2; ++a)
        #pragma unroll
        for (int i = 0; i < 4; ++i)
            #pragma unroll
            for (int b = 0; b < 2; ++b)
                #pragma unroll
                for (int j = 0; j < 2; ++j)
                    acc[a][i][b][j] = (f32x4){0.f, 0.f, 0.f, 0.f};

    // staging: 512 threads cover 64 rows x 128B per call (8 lanes/row).
    // row within call = w*8 + (lane>>3); slot lane&7 holds chunk
    // q = (lane&7) ^ ((lane>>3)&7); q<4 -> hi k q*8.., q>=4 -> lo k (q-4)*8..
    const int srow = w * 8 + (lane >> 3);
    const int q    = (lane & 7) ^ ((lane >> 3) & 7);
    const int qoff = (q < 4) ? q * 8 : K + (q - 4) * 8;
    const __bf16* Ab = A + (long)(bm + srow) * lda + qoff;
    const __bf16* Bb = B + (long)(bn + srow) * ldb + qoff;
    const long lda64 = 64 * lda, ldb64 = 64 * ldb;
    const int wo = w * 1024;            // wave's 8-row slice within a call

    const int fr = lane & 15;
    const int g4 = lane >> 4;           // k-chunk group 0..3 within 32-k tile

    // reads confined per 128-row half (R14 mapping — harness-verified)
    auto rdA = [&](int ih, bf16x8 (&aH)[4], bf16x8 (&aL)[4]) {
        #pragma unroll
        for (int t = 0; t < 4; ++t) {
            const int ra = aw + ih * 128 + t * 16 + fr;
            aH[t] = *(const bf16x8*)&Asl[ra * 64 + ((g4       ^ (ra & 7)) * 8)];
            aL[t] = *(const bf16x8*)&Asl[ra * 64 + (((4 + g4) ^ (ra & 7)) * 8)];
        }
    };
    auto rdB = [&](int jh, bf16x8 (&bH)[2], bf16x8 (&bL)[2]) {
        #pragma unroll
        for (int t = 0; t < 2; ++t) {
            const int rb = bw + jh * 128 + t * 16 + fr;
            bH[t] = *(const bf16x8*)&Bsl[rb * 64 + ((g4       ^ (rb & 7)) * 8)];
            bL[t] = *(const bf16x8*)&Bsl[rb * 64 + (((4 + g4) ^ (rb & 7)) * 8)];
        }
    };

    for (int kk = 0; kk < K; kk += 32) {
        __syncthreads();
        #pragma unroll
        for (int j = 0; j < 4; ++j) {
            async_copy16(Ab + kk + j * lda64, (char*)Asl + j * 8192 + wo);
            async_copy16(Bb + kk + j * ldb64, (char*)Bsl + j * 8192 + wo);
        }
        __syncthreads();

        bf16x8 aH[4], aL[4], bH[2], bL[2];
        rdA(0, aH, aL);
        rdB(0, bH, bL);
        quad24<0, 0>(acc, aH, aL, bH, bL);
        rdB(1, bH, bL);
        quad24<0, 1>(acc, aH, aL, bH, bL);
        rdA(1, aH, aL);
        quad24<1, 1>(acc, aH, aL, bH, bL);
        rdB(0, bH, bL);
        quad24<1, 0>(acc, aH, aL, bH, bL);
    }

    // C/D layout (m89-verified): col = lane&15, row = (lane>>4)*4 + reg
    const int cn  = lane & 15;
    const int cr4 = (lane >> 4) * 4;
    #pragma unroll
    for (int ih = 0; ih < 2; ++ih)
        #pragma unroll
        for (int i = 0; i < 4; ++i)
            #pragma unroll
            for (int jh = 0; jh < 2; ++jh)
                #pragma unroll
                for (int j = 0; j < 2; ++j)
                    #pragma unroll
                    for (int r = 0; r < 4; ++r) {
                        const int row = bm + aw + ih * 128 + i * 16 + cr4 + r;
                        const int col = bn + bw + jh * 128 + j * 16 + cn;
                        C[(long)row * ldc + col] = acc[ih][i][jh][j][r];
                    }
}

// ---------------------------------------------------------------------------
// Split-bf16 MFMA GEMM (NT), SINGLE-PASS K (R10 — known-good): per 32-k tile,
// stage all four panels once and fire all three products.  128x128 tile,
// 4 waves of 64x64 (4x4 of 16x16x32).  K % 32 == 0.
// LDS swizzle = R8 (verified conflicts=0).
// EPI 0: plain store.  EPI 1: softplus(v + bias[col]) (dt epilogue).
// ---------------------------------------------------------------------------
template <int EPI>
__global__ __launch_bounds__(256)
void gemm_f(const __bf16* __restrict__ A, const __bf16* __restrict__ B,
            float* __restrict__ C, const float* __restrict__ bias,
            int M, int N, int K, int ldc)
{
    __shared__ __bf16 Asl[128 * 64];
    __shared__ __bf16 Bsl[128 * 64];

    const int tid  = threadIdx.x;
    const int lane = tid & 63;
    const int w    = tid >> 6;
    const int wm   = (w >> 1) * 64;
    const int wn   = (w & 1) * 64;

    const int bm = blockIdx.y * 128;
    const int bn = blockIdx.x * 128;

    const long lda = 2L * K;
    const long ldb = 2L * K;

    f32x4 acc[4][4];
    #pragma unroll
    for (int i = 0; i < 4; ++i)
        #pragma unroll
        for (int j = 0; j < 4; ++j)
            acc[i][j] = (f32x4){0.f, 0.f, 0.f, 0.f};

    const int srow = w * 32 + (lane >> 3);
    const int q    = (lane & 7) ^ ((lane >> 3) & 7);
    const int qoff = (q < 4) ? q * 8 : K + (q - 4) * 8;
    const __bf16* Abase = A + (long)(bm + srow) * lda + qoff;
    const __bf16* Bbase = B + (long)(bn + srow) * ldb + qoff;
    char* AslW = (char*)Asl + (w * 32) * 128;
    char* BslW = (char*)Bsl + (w * 32) * 128;

    const int fr = lane & 15;
    const int g4 = lane >> 4;          // k-chunk group 0..3 within 32-k tile
    const long lda8 = 8 * lda, ldb8 = 8 * ldb;

    for (int kk = 0; kk < K; kk += 32) {
        __syncthreads();
        #pragma unroll
        for (int j = 0; j < 4; ++j) {
            async_copy16(Abase + j * lda8 + kk, AslW + j * 1024);
            async_copy16(Bbase + j * ldb8 + kk, BslW + j * 1024);
        }
        __syncthreads();

        bf16x8 ah[4], al[4], bh[4], bl[4];
        #pragma unroll
        for (int t = 0; t < 4; ++t) {
            const int ra = wm + t * 16 + fr;
            const int rb = wn + t * 16 + fr;
            ah[t] = *(const bf16x8*)&Asl[ra * 64 + ((g4       ^ (ra & 7)) * 8)];
            al[t] = *(const bf16x8*)&Asl[ra * 64 + (((4 + g4) ^ (ra & 7)) * 8)];
            bh[t] = *(const bf16x8*)&Bsl[rb * 64 + ((g4       ^ (rb & 7)) * 8)];
            bl[t] = *(const bf16x8*)&Bsl[rb * 64 + (((4 + g4) ^ (rb & 7)) * 8)];
        }
        #pragma unroll
        for (int i = 0; i < 4; ++i)
            #pragma unroll
            for (int j = 0; j < 4; ++j) {
                acc[i][j] = __builtin_amdgcn_mfma_f32_16x16x32_bf16(ah[i], bh[j], acc[i][j], 0, 0, 0);
                acc[i][j] = __builtin_amdgcn_mfma_f32_16x16x32_bf16(ah[i], bl[j], acc[i][j], 0, 0, 0);
                acc[i][j] = __builtin_amdgcn_mfma_f32_16x16x32_bf16(al[i], bh[j], acc[i][j], 0, 0, 0);
            }
    }

    // C/D layout (m89-verified): col = lane&15, row = (lane>>4)*4 + reg
    const int cn  = lane & 15;
    const int cr4 = (lane >> 4) * 4;
    #pragma unroll
    for (int i = 0; i < 4; ++i)
        #pragma unroll
        for (int j = 0; j < 4; ++j)
            #pragma unroll
            for (int r = 0; r < 4; ++r) {
                const int row = bm + wm + i * 16 + cr4 + r;
                const int col = bn + wn + j * 16 + cn;
                float v = acc[i][j][r];
                if (EPI == 1) {
                    v += bias[col];
                    v = fmaxf(v, 0.f) + log1pf(__expf(-fabsf(v)));  // stable softplus
                }
                C[(long)row * ldc + col] = v;
            }
}

// ---------------------------------------------------------------------------
// x_dbl split-K MFMA GEMM, single-pass K (R10): A = xcS (8192 x 3072 split),
// B = W_xS (128-row padded, 80 valid), K=1536 -> 48 k-tiles split 4 ways.
// grid(4, 64); partials to Pout[s][8192][128].
// ---------------------------------------------------------------------------
__global__ __launch_bounds__(256)
void gemm_xdbl(const __bf16* __restrict__ A, const __bf16* __restrict__ B,
               float* __restrict__ Pout)
{
    __shared__ __bf16 Asl[128 * 64];
    __shared__ __bf16 Bsl[128 * 64];

    const int tid  = threadIdx.x;
    const int lane = tid & 63;
    const int w    = tid >> 6;
    const int wm   = (w >> 1) * 64;
    const int wn   = (w & 1) * 64;

    const int s  = blockIdx.x;           // split-K index 0..3
    const int bm = blockIdx.y * 128;
    const int K  = 1536;
    const long lda = 3072, ldb = 3072;

    f32x4 acc[4][4];
    #pragma unroll
    for (int i = 0; i < 4; ++i)
        #pragma unroll
        for (int j = 0; j < 4; ++j)
            acc[i][j] = (f32x4){0.f, 0.f, 0.f, 0.f};

    const int srow = w * 32 + (lane >> 3);
    const int q    = (lane & 7) ^ ((lane >> 3) & 7);
    const int qoff = (q < 4) ? q * 8 : K + (q - 4) * 8;
    const __bf16* Abase = A + (long)(bm + srow) * lda + qoff;
    const __bf16* Bbase = B + (long)srow * ldb + qoff;
    char* AslW = (char*)Asl + (w * 32) * 128;
    char* BslW = (char*)Bsl + (w * 32) * 128;

    const int fr = lane & 15;
    const int g4 = lane >> 4;
    const long lda8 = 8 * lda, ldb8 = 8 * ldb;

    for (int kt = s * 12; kt < (s + 1) * 12; ++kt) {
        const int kk = kt * 32;
        __syncthreads();
        #pragma unroll
        for (int j = 0; j < 4; ++j) {
            async_copy16(Abase + j * lda8 + kk, AslW + j * 1024);
            async_copy16(Bbase + j * ldb8 + kk, BslW + j * 1024);
        }
        __syncthreads();

        bf16x8 ah[4], al[4], bh[4], bl[4];
        #pragma unroll
        for (int t = 0; t < 4; ++t) {
            const int ra = wm + t * 16 + fr;
            const int rb = wn + t * 16 + fr;
            ah[t] = *(const bf16x8*)&Asl[ra * 64 + ((g4       ^ (ra & 7)) * 8)];
            al[t] = *(const bf16x8*)&Asl[ra * 64 + (((4 + g4) ^ (ra & 7)) * 8)];
            bh[t] = *(const bf16x8*)&Bsl[rb * 64 + ((g4       ^ (rb & 7)) * 8)];
            bl[t] = *(const bf16x8*)&Bsl[rb * 64 + (((4 + g4) ^ (rb & 7)) * 8)];
        }
        #pragma unroll
        for (int i = 0; i < 4; ++i)
            #pragma unroll
            for (int j = 0; j < 4; ++j) {
                acc[i][j] = __builtin_amdgcn_mfma_f32_16x16x32_bf16(ah[i], bh[j], acc[i][j], 0, 0, 0);
                acc[i][j] = __builtin_amdgcn_mfma_f32_16x16x32_bf16(ah[i], bl[j], acc[i][j], 0, 0, 0);
                acc[i][j] = __builtin_amdgcn_mfma_f32_16x16x32_bf16(al[i], bh[j], acc[i][j], 0, 0, 0);
            }
    }

    float* Cp = Pout + (long)s * (8192L * 128);
    const int cn  = lane & 15;
    const int cr4 = (lane >> 4) * 4;
    #pragma unroll
    for (int i = 0; i < 4; ++i)
        #pragma unroll
        for (int j = 0; j < 4; ++j)
            #pragma unroll
            for (int r = 0; r < 4; ++r) {
                const int row = bm + wm + i * 16 + cr4 + r;
                const int col = wn + j * 16 + cn;
                Cp[(long)row * 128 + col] = acc[i][j][r];
            }
}

// ---------------------------------------------------------------------------
// Reduce 4 split-K partials into (a) xbc (8192 x 32, B/C cols 48..79) and
// (b) xdtS (8192 x 128 padded split: hi of k 0..47 at cols 0..47, lo at
// 64..111, zero pads) — the dt-GEMM A operand.
// ---------------------------------------------------------------------------
__global__ __launch_bounds__(256)
void xdbl_reduce3(const float* __restrict__ Pout, float* __restrict__ xbc,
                  __bf16* __restrict__ xdtS)
{
    const long i = (long)blockIdx.x * 256 + threadIdx.x;   // over 8192*128
    if (i >= 8192L * 128) return;
    const long r  = i >> 7;
    const int  c  = (int)(i & 127);
    const long st = 8192L * 128;
    const long rb = r * 128;

    const int k = c & 63;
    float u = 0.f;
    if (k < 48) {
        const long o = rb + k;
        u = (Pout[o] + Pout[o + st]) + (Pout[o + 2 * st] + Pout[o + 3 * st]);
    }
    const __bf16 hi = (__bf16)u;
    xdtS[rb + c] = (c < 64) ? hi : (__bf16)(u - (float)hi);

    if (c >= 96) {                      // cols 96..127 also emit xbc 0..31
        const int j = c - 96;
        const long o = rb + 48 + j;
        xbc[r * 32 + j] =
            (Pout[o] + Pout[o + st]) + (Pout[o + 2 * st] + Pout[o + 3 * st]);
    }
}

// ---------------------------------------------------------------------------
// Merged input/weight split: x, W_in, W_out, W_x, W_dt (padded 1536x128).
// ---------------------------------------------------------------------------
#define NW0 ((long)BL * 768)
#define NW1 (3072L * 768)
#define NW2 (768L * 1536)
#define NW3 (80L * 1536)
#define NW4 (1536L * 128)
__global__ __launch_bounds__(256)
void split_all(const float* __restrict__ x,
               const float* __restrict__ W_in, const float* __restrict__ W_out,
               const float* __restrict__ W_x, const float* __restrict__ W_dt,
               __bf16* __restrict__ xS,
               __bf16* __restrict__ wInS, __bf16* __restrict__ wOutS,
               __bf16* __restrict__ wXS, __bf16* __restrict__ wDtS)
{
    long i = (long)blockIdx.x * 256 + threadIdx.x;
    if (i < NW0) {
        const long row = i / 768; const int col = (int)(i - row * 768);
        const float a = x[i];
        const __bf16 h = (__bf16)a;
        __bf16* d = xS + row * 1536 + col;
        d[0] = h; d[768] = (__bf16)(a - (float)h);
        return;
    }
    i -= NW0;
    if (i < NW1) {
        const long row = i / 768; const int col = (int)(i - row * 768);
        const float a = W_in[i];
        const __bf16 h = (__bf16)a;
        __bf16* d = wInS + row * 1536 + col;
        d[0] = h; d[768] = (__bf16)(a - (float)h);
        return;
    }
    i -= NW1;
    if (i < NW2) {
        const long row = i / 1536; const int col = (int)(i - row * 1536);
        const float a = W_out[i];
        const __bf16 h = (__bf16)a;
        __bf16* d = wOutS + row * 3072 + col;
        d[0] = h; d[1536] = (__bf16)(a - (float)h);
        return;
    }
    i -= NW2;
    if (i < NW3) {
        const long row = i / 1536; const int col = (int)(i - row * 1536);
        const float a = W_x[i];
        const __bf16 h = (__bf16)a;
        __bf16* d = wXS + row * 3072 + col;
        d[0] = h; d[1536] = (__bf16)(a - (float)h);
        return;
    }
    i -= NW3;
    if (i < NW4) {
        const long row = i >> 7; const int c = (int)(i & 127);
        const int k = c & 63;
        const float a = (k < 48) ? W_dt[row * 48 + k] : 0.f;
        const __bf16 h = (__bf16)a;
        wDtS[row * 128 + c] = (c < 64) ? h : (__bf16)(a - (float)h);
    }
}

// ---------------------------------------------------------------------------
// Depthwise causal conv (width 4) + bias + SiLU -> xcS split-bf16.
// ---------------------------------------------------------------------------
__global__ __launch_bounds__(256)
void conv_silu_kernel(const float* __restrict__ xz,
                      const float* __restrict__ conv_w,
                      const float* __restrict__ conv_b,
                      __bf16* __restrict__ xcS)
{
    const long idx = (long)blockIdx.x * 256 + threadIdx.x;
    const int d  = (int)(idx % D_INNER);
    const long bl = idx / D_INNER;
    const int l  = (int)(bl % SEQ_LEN);

    const float w0 = conv_w[d * 4 + 0];
    const float w1 = conv_w[d * 4 + 1];
    const float w2 = conv_w[d * 4 + 2];
    const float w3 = conv_w[d * 4 + 3];

    const float* base = xz + bl * 3072 + d;
    float s = conv_b[d];
    if (l >= 3) s = fmaf(base[-3 * 3072], w0, s);
    if (l >= 2) s = fmaf(base[-2 * 3072], w1, s);
    if (l >= 1) s = fmaf(base[-1 * 3072], w2, s);
    s = fmaf(base[0], w3, s);
    const float sig = 1.f / (1.f + __expf(-s));
    const float v = s * sig;
    const __bf16 hi = (__bf16)v;
    const __bf16 lo = (__bf16)(v - (float)hi);
    xcS[bl * 3072 + d]        = hi;
    xcS[bl * 3072 + 1536 + d] = lo;
}

// ---------------------------------------------------------------------------
// Scan phase A: per (b, d, chunk): P = prod(a_l), S = local scan (h0=0).
// B/C from xbc (8192 x 32: B_t = [0:16], C_t = [16:32]).
// ---------------------------------------------------------------------------
__global__ __launch_bounds__(256)
void scan_phaseA(const __bf16* __restrict__ xcS, const float* __restrict__ xz,
                 const float* __restrict__ xbc, const float* __restrict__ A_log,
                 float* __restrict__ P, float* __restrict__ S)
{
    const int d = blockIdx.x * 256 + threadIdx.x;
    const int c = blockIdx.y;
    const int b = blockIdx.z;

    float An[16], Pr[16], Sr[16];
    #pragma unroll
    for (int n = 0; n < 16; ++n) {
        An[n] = -__expf(A_log[d * 16 + n]);
        Pr[n] = 1.f;
        Sr[n] = 0.f;
    }

    const long bl0 = (long)b * SEQ_LEN + (long)c * CHUNK;
    for (int l = 0; l < CHUNK; ++l) {
        const long bl = bl0 + l;
        const float dt  = xz[bl * 3072 + d];
        const float x   = (float)xcS[bl * 3072 + d] + (float)xcS[bl * 3072 + 1536 + d];
        const float dtx = dt * x;
        const float* bc = xbc + bl * 32;
        #pragma unroll
        for (int n = 0; n < 16; ++n) {
            const float a = __expf(dt * An[n]);
            Pr[n] *= a;
            Sr[n] = fmaf(a, Sr[n], dtx * bc[n]);
        }
    }

    const long base = ((long)(b * NCHUNK + c) * 16) * D_INNER + d;
    #pragma unroll
    for (int n = 0; n < 16; ++n) {
        P[base + (long)n * D_INNER] = Pr[n];
        S[base + (long)n * D_INNER] = Sr[n];
    }
}

// ---------------------------------------------------------------------------
// Scan phase B: one thread per (b, n, d) — 384 blocks, coalesced over d.
// ---------------------------------------------------------------------------
__global__ __launch_bounds__(256)
void scan_phaseB(const float* __restrict__ P, const float* __restrict__ S,
                 float* __restrict__ H)
{
    const int t = blockIdx.x * 256 + threadIdx.x;   // over BATCH*16*D_INNER
    const int d = t % D_INNER;
    const int r = t / D_INNER;
    const int n = r & 15;
    const int b = r >> 4;

    float h = 0.f;
    for (int c = 0; c < NCHUNK; ++c) {
        const long i = ((long)(b * NCHUNK + c) * 16 + n) * D_INNER + d;
        H[i] = h;
        h = fmaf(P[i], h, S[i]);
    }
}

// ---------------------------------------------------------------------------
// Scan phase C: re-run chunks from h_in, emit y, gate with silu(z), write
// split-bf16 in-place over xcS -> yS.
// ---------------------------------------------------------------------------
__global__ __launch_bounds__(256)
void scan_phaseC(__bf16* xcS_yS, const float* __restrict__ xz,
                 const float* __restrict__ xbc, const float* __restrict__ A_log,
                 const float* __restrict__ Dp, const float* __restrict__ H)
{
    const int d = blockIdx.x * 256 + threadIdx.x;
    const int c = blockIdx.y;
    const int b = blockIdx.z;

    float An[16], h[16];
    const long hbase = ((long)(b * NCHUNK + c) * 16) * D_INNER + d;
    #pragma unroll
    for (int n = 0; n < 16; ++n) {
        An[n] = -__expf(A_log[d * 16 + n]);
        h[n]  = H[hbase + (long)n * D_INNER];
    }
    const float Dd = Dp[d];

    const long bl0 = (long)b * SEQ_LEN + (long)c * CHUNK;
    for (int l = 0; l < CHUNK; ++l) {
        const long bl = bl0 + l;
        const float dt  = xz[bl * 3072 + d];
        const float x   = (float)xcS_yS[bl * 3072 + d] + (float)xcS_yS[bl * 3072 + 1536 + d];
        const float dtx = dt * x;
        const float* bc = xbc + bl * 32;
        float y = Dd * x;
        #pragma unroll
        for (int n = 0; n < 16; ++n) {
            const float a = __expf(dt * An[n]);
            h[n] = fmaf(a, h[n], dtx * bc[n]);
            y = fmaf(h[n], bc[16 + n], y);
        }
        const float z  = xz[bl * 3072 + D_INNER + d];
        const float sz = z / (1.f + __expf(-z));
        const float v  = y * sz;
        const __bf16 hi = (__bf16)v;
        const __bf16 lo = (__bf16)(v - (float)hi);
        xcS_yS[bl * 3072 + d]        = hi;
        xcS_yS[bl * 3072 + 1536 + d] = lo;
    }
}

// ---------------------------------------------------------------------------
extern "C" void kernel_launch(void* const* d_in, const int* in_sizes, int n_in,
                              void* d_out, int out_size, void* d_ws, size_t ws_size,
                              hipStream_t stream)
{
    const float* x      = (const float*)d_in[0];   // (4,2048,768)
    const float* W_in   = (const float*)d_in[1];   // (3072,768)
    const float* conv_w = (const float*)d_in[2];   // (1536,1,4)
    const float* conv_b = (const float*)d_in[3];   // (1536,)
    const float* W_x    = (const float*)d_in[4];   // (80,1536)
    const float* W_dt   = (const float*)d_in[5];   // (1536,48)
    const float* b_dt   = (const float*)d_in[6];   // (1536,)
    const float* A_log  = (const float*)d_in[7];   // (1536,16)
    const float* D_p    = (const float*)d_in[8];   // (1536,)
    const float* W_out  = (const float*)d_in[9];   // (768,1536)
    float* out = (float*)d_out;                    // (4,2048,768)

    // ---- workspace carve, ~202 MB ---------------------------------------
    char* p = (char*)d_ws;
    auto take = [&](size_t bytes) { char* r = p; p += (bytes + 255) & ~(size_t)255; return r; };

    float*  xz    = (float*)take((size_t)BL * 3072 * 4);    // 100.7 MB (dt | z)
    float*  H     = (float*)take((size_t)BATCH * NCHUNK * 16 * D_INNER * 4); // 12.6 MB
    __bf16* wOutS = (__bf16*)take(768L * 3072 * 2);         //   4.7 MB
    __bf16* wXS   = (__bf16*)take(128L * 3072 * 2);         //   0.8 MB (80 valid)
    __bf16* wDtS  = (__bf16*)take(1536L * 128 * 2);         //   0.4 MB
    __bf16* xdtS  = (__bf16*)take(8192L * 128 * 2);         //   2.1 MB
    float*  xbc   = (float*)take(8192L * 32 * 4);           //   1.0 MB
    float*  Pout  = (float*)take(4L * 8192 * 128 * 4);      //  16.8 MB (-> P overlay)
    float*  S     = (float*)take((size_t)BATCH * NCHUNK * 16 * D_INNER * 4); // 12.6 MB
    float*  P     = Pout;   // Pout dead after xdbl_reduce3; P needs 12.6 MB

    // REGION (50.4 MB), time-multiplexed:
    //   phase 1:   xS (25.2MB) + wInS (9.4MB)
    //   phase 2-8: xcS (8192x3072 bf16), phaseC overwrites in-place -> yS
    char* region = take(50331648);
    __bf16* xS   = (__bf16*)region;
    __bf16* wInS = (__bf16*)(region + 25165824);
    __bf16* xcS  = (__bf16*)region;
    __bf16* yS   = (__bf16*)region;

    // 0) split conversions (x + weights, one launch)
    {
        const long n = NW0 + NW1 + NW2 + NW3 + NW4;
        split_all<<<(int)((n + 255) / 256), 256, 0, stream>>>(
            x, W_in, W_out, W_x, W_dt, xS, wInS, wOutS, wXS, wDtS);
    }
    // 1) xz = x @ W_in^T  (256x256 single-buffered co-resident MFMA, K=768)
    {
        dim3 grid(3072 / 256, BL / 256);   // 12 x 32 = 384 blocks, 2/CU
        gemm256<<<grid, 512, 0, stream>>>(xS, wInS, xz, 768, 3072);
    }
    // 2) conv + bias + SiLU -> xcS (overlays xS)
    {
        const long total = (long)BL * D_INNER;
        conv_silu_kernel<<<(int)(total / 256), 256, 0, stream>>>(xz, conv_w, conv_b, xcS);
    }
    // 3) x_dbl split-K MFMA -> Pout
    {
        dim3 grid(4, BL / 128);
        gemm_xdbl<<<grid, 256, 0, stream>>>(xcS, wXS, Pout);
    }
    // 4) reduce partials -> xbc + xdtS
    {
        const long n = 8192L * 128;
        xdbl_reduce3<<<(int)((n + 255) / 256), 256, 0, stream>>>(Pout, xbc, xdtS);
    }
    // 5) dt = softplus(xdt @ W_dt^T + b_dt)  (R10 MFMA, K=64 padded)
    {
        dim3 grid(1536 / 128, BL / 128);
        gemm_f<1><<<grid, 256, 0, stream>>>(xdtS, wDtS, xz, b_dt,
                                            BL, 1536, 64, 3072);
    }
    // 6) scan phase A  (P overlays dead Pout)
    {
        dim3 grid(D_INNER / 256, NCHUNK, BATCH);
        scan_phaseA<<<grid, 256, 0, stream>>>(xcS, xz, xbc, A_log, P, S);
    }
    // 7) scan phase B (per-(b,n,d): 384 blocks)
    scan_phaseB<<<(BATCH * 16 * D_INNER) / 256, 256, 0, stream>>>(P, S, H);
    // 8) scan phase C: xcS -> yS in-place
    {
        dim3 grid(D_INNER / 256, NCHUNK, BATCH);
        scan_phaseC<<<grid, 256, 0, stream>>>(xcS, xz, xbc, A_log, D_p, H);
    }
    // 9) out = y @ W_out^T  (R10 MFMA, M=8192, N=768, K=1536)
    {
        dim3 grid(768 / 128, BL / 128);
        gemm_f<0><<<grid, 256, 0, stream>>>(yS, wOutS, out, nullptr,
                                            BL, 768, 1536, 768);
    }
}

// Round 7
// 581.858 us; speedup vs baseline: 2.2466x; 2.2466x over previous
//
#include <hip/hip_runtime.h>
#include <hip/hip_bf16.h>
#include <math.h>

// Problem constants (fixed by reference)
#define D_MODEL   768
#define D_STATE   16
#define D_CONV    4
#define D_INNER   1536
#define DT_RANK   48
#define BATCH     4
#define SEQ_LEN   2048
#define BL        (BATCH * SEQ_LEN)        // 8192 rows
#define NCHUNK    32
#define CHUNK     (SEQ_LEN / NCHUNK)       // 64

typedef __bf16 bf16x8 __attribute__((ext_vector_type(8)));
typedef float  f32x4  __attribute__((ext_vector_type(4)));

__device__ __forceinline__ void async_copy16(const void* g, void* l) {
    __builtin_amdgcn_global_load_lds(
        (const __attribute__((address_space(1))) void*)g,
        (__attribute__((address_space(3))) void*)l,
        16, 0, 0);
}

// ===========================================================================
// R17 step-1 kernel: identical to R16 (256x256, 8 waves, single-buffered
// 64 KB LDS, plain 2-barrier K-loop) EXCEPT __launch_bounds__(512, 2).
// R16's (512,4) capped regs at 128/thread; on gfx950's UNIFIED VGPR/AGPR
// file the compiler split 64V+64A -> massive scratch spill (VGPR_Count=64,
// FETCH 1.5 GB, WRITE 2.3 GB, MfmaUtil 5%, 890 us).  (512,2) = 256-reg cap;
// R14 measured 112 VGPR under this bound, no spill.
// Occupancy: LDS 64 KB -> 2 blocks/CU co-resident (the R16 goal): barrier
// drain of one block hides under the other's 96-MFMA tile (m114 overlap).
// ===========================================================================

template<int IH, int JH>
__device__ __forceinline__ void quad24(f32x4 (&acc)[2][4][2][2],
                                       const bf16x8 (&aH)[4], const bf16x8 (&aL)[4],
                                       const bf16x8 (&bH)[2], const bf16x8 (&bL)[2])
{
    #pragma unroll
    for (int i = 0; i < 4; ++i)
        #pragma unroll
        for (int j = 0; j < 2; ++j) {
            acc[IH][i][JH][j] = __builtin_amdgcn_mfma_f32_16x16x32_bf16(aH[i], bH[j], acc[IH][i][JH][j], 0, 0, 0);
            acc[IH][i][JH][j] = __builtin_amdgcn_mfma_f32_16x16x32_bf16(aH[i], bL[j], acc[IH][i][JH][j], 0, 0, 0);
            acc[IH][i][JH][j] = __builtin_amdgcn_mfma_f32_16x16x32_bf16(aL[i], bH[j], acc[IH][i][JH][j], 0, 0, 0);
        }
}

__global__ __launch_bounds__(512, 2)
void gemm256(const __bf16* __restrict__ A, const __bf16* __restrict__ B,
             float* __restrict__ C, int K, int ldc)
{
    __shared__ __bf16 Asl[256 * 64];    // 32 KB
    __shared__ __bf16 Bsl[256 * 64];    // 32 KB

    const int tid  = threadIdx.x;
    const int lane = tid & 63;
    const int w    = tid >> 6;          // 0..7
    const int aw   = (w >> 2) * 64;     // A sub-slice within each 128-row half
    const int bw   = (w & 3) * 32;      // B sub-slice within each 128-row half

    const int bm = blockIdx.y * 256;
    const int bn = blockIdx.x * 256;

    const long lda = 2L * K;
    const long ldb = 2L * K;

    f32x4 acc[2][4][2][2];
    #pragma unroll
    for (int a = 0; a < 2; ++a)
        #pragma unroll
        for (int i = 0; i < 4; ++i)
            #pragma unroll
            for (int b = 0; b < 2; ++b)
                #pragma unroll
                for (int j = 0; j < 2; ++j)
                    acc[a][i][b][j] = (f32x4){0.f, 0.f, 0.f, 0.f};

    // staging: 512 threads cover 64 rows x 128B per call (8 lanes/row).
    // row within call = w*8 + (lane>>3); slot lane&7 holds chunk
    // q = (lane&7) ^ ((lane>>3)&7); q<4 -> hi k q*8.., q>=4 -> lo k (q-4)*8..
    const int srow = w * 8 + (lane >> 3);
    const int q    = (lane & 7) ^ ((lane >> 3) & 7);
    const int qoff = (q < 4) ? q * 8 : K + (q - 4) * 8;
    const __bf16* Ab = A + (long)(bm + srow) * lda + qoff;
    const __bf16* Bb = B + (long)(bn + srow) * ldb + qoff;
    const long lda64 = 64 * lda, ldb64 = 64 * ldb;
    const int wo = w * 1024;            // wave's 8-row slice within a call

    const int fr = lane & 15;
    const int g4 = lane >> 4;           // k-chunk group 0..3 within 32-k tile

    // reads confined per 128-row half (R14 mapping — harness-verified)
    auto rdA = [&](int ih, bf16x8 (&aH)[4], bf16x8 (&aL)[4]) {
        #pragma unroll
        for (int t = 0; t < 4; ++t) {
            const int ra = aw + ih * 128 + t * 16 + fr;
            aH[t] = *(const bf16x8*)&Asl[ra * 64 + ((g4       ^ (ra & 7)) * 8)];
            aL[t] = *(const bf16x8*)&Asl[ra * 64 + (((4 + g4) ^ (ra & 7)) * 8)];
        }
    };
    auto rdB = [&](int jh, bf16x8 (&bH)[2], bf16x8 (&bL)[2]) {
        #pragma unroll
        for (int t = 0; t < 2; ++t) {
            const int rb = bw + jh * 128 + t * 16 + fr;
            bH[t] = *(const bf16x8*)&Bsl[rb * 64 + ((g4       ^ (rb & 7)) * 8)];
            bL[t] = *(const bf16x8*)&Bsl[rb * 64 + (((4 + g4) ^ (rb & 7)) * 8)];
        }
    };

    for (int kk = 0; kk < K; kk += 32) {
        __syncthreads();
        #pragma unroll
        for (int j = 0; j < 4; ++j) {
            async_copy16(Ab + kk + j * lda64, (char*)Asl + j * 8192 + wo);
            async_copy16(Bb + kk + j * ldb64, (char*)Bsl + j * 8192 + wo);
        }
        __syncthreads();

        bf16x8 aH[4], aL[4], bH[2], bL[2];
        rdA(0, aH, aL);
        rdB(0, bH, bL);
        quad24<0, 0>(acc, aH, aL, bH, bL);
        rdB(1, bH, bL);
        quad24<0, 1>(acc, aH, aL, bH, bL);
        rdA(1, aH, aL);
        quad24<1, 1>(acc, aH, aL, bH, bL);
        rdB(0, bH, bL);
        quad24<1, 0>(acc, aH, aL, bH, bL);
    }

    // C/D layout (m89-verified): col = lane&15, row = (lane>>4)*4 + reg
    const int cn  = lane & 15;
    const int cr4 = (lane >> 4) * 4;
    #pragma unroll
    for (int ih = 0; ih < 2; ++ih)
        #pragma unroll
        for (int i = 0; i < 4; ++i)
            #pragma unroll
            for (int jh = 0; jh < 2; ++jh)
                #pragma unroll
                for (int j = 0; j < 2; ++j)
                    #pragma unroll
                    for (int r = 0; r < 4; ++r) {
                        const int row = bm + aw + ih * 128 + i * 16 + cr4 + r;
                        const int col = bn + bw + jh * 128 + j * 16 + cn;
                        C[(long)row * ldc + col] = acc[ih][i][jh][j][r];
                    }
}

// ---------------------------------------------------------------------------
// Split-bf16 MFMA GEMM (NT), SINGLE-PASS K (R10 — known-good): per 32-k tile,
// stage all four panels once and fire all three products.  128x128 tile,
// 4 waves of 64x64 (4x4 of 16x16x32).  K % 32 == 0.
// LDS swizzle = R8 (verified conflicts=0).
// EPI 0: plain store.  EPI 1: softplus(v + bias[col]) (dt epilogue).
// ---------------------------------------------------------------------------
template <int EPI>
__global__ __launch_bounds__(256)
void gemm_f(const __bf16* __restrict__ A, const __bf16* __restrict__ B,
            float* __restrict__ C, const float* __restrict__ bias,
            int M, int N, int K, int ldc)
{
    __shared__ __bf16 Asl[128 * 64];
    __shared__ __bf16 Bsl[128 * 64];

    const int tid  = threadIdx.x;
    const int lane = tid & 63;
    const int w    = tid >> 6;
    const int wm   = (w >> 1) * 64;
    const int wn   = (w & 1) * 64;

    const int bm = blockIdx.y * 128;
    const int bn = blockIdx.x * 128;

    const long lda = 2L * K;
    const long ldb = 2L * K;

    f32x4 acc[4][4];
    #pragma unroll
    for (int i = 0; i < 4; ++i)
        #pragma unroll
        for (int j = 0; j < 4; ++j)
            acc[i][j] = (f32x4){0.f, 0.f, 0.f, 0.f};

    const int srow = w * 32 + (lane >> 3);
    const int q    = (lane & 7) ^ ((lane >> 3) & 7);
    const int qoff = (q < 4) ? q * 8 : K + (q - 4) * 8;
    const __bf16* Abase = A + (long)(bm + srow) * lda + qoff;
    const __bf16* Bbase = B + (long)(bn + srow) * ldb + qoff;
    char* AslW = (char*)Asl + (w * 32) * 128;
    char* BslW = (char*)Bsl + (w * 32) * 128;

    const int fr = lane & 15;
    const int g4 = lane >> 4;          // k-chunk group 0..3 within 32-k tile
    const long lda8 = 8 * lda, ldb8 = 8 * ldb;

    for (int kk = 0; kk < K; kk += 32) {
        __syncthreads();
        #pragma unroll
        for (int j = 0; j < 4; ++j) {
            async_copy16(Abase + j * lda8 + kk, AslW + j * 1024);
            async_copy16(Bbase + j * ldb8 + kk, BslW + j * 1024);
        }
        __syncthreads();

        bf16x8 ah[4], al[4], bh[4], bl[4];
        #pragma unroll
        for (int t = 0; t < 4; ++t) {
            const int ra = wm + t * 16 + fr;
            const int rb = wn + t * 16 + fr;
            ah[t] = *(const bf16x8*)&Asl[ra * 64 + ((g4       ^ (ra & 7)) * 8)];
            al[t] = *(const bf16x8*)&Asl[ra * 64 + (((4 + g4) ^ (ra & 7)) * 8)];
            bh[t] = *(const bf16x8*)&Bsl[rb * 64 + ((g4       ^ (rb & 7)) * 8)];
            bl[t] = *(const bf16x8*)&Bsl[rb * 64 + (((4 + g4) ^ (rb & 7)) * 8)];
        }
        #pragma unroll
        for (int i = 0; i < 4; ++i)
            #pragma unroll
            for (int j = 0; j < 4; ++j) {
                acc[i][j] = __builtin_amdgcn_mfma_f32_16x16x32_bf16(ah[i], bh[j], acc[i][j], 0, 0, 0);
                acc[i][j] = __builtin_amdgcn_mfma_f32_16x16x32_bf16(ah[i], bl[j], acc[i][j], 0, 0, 0);
                acc[i][j] = __builtin_amdgcn_mfma_f32_16x16x32_bf16(al[i], bh[j], acc[i][j], 0, 0, 0);
            }
    }

    // C/D layout (m89-verified): col = lane&15, row = (lane>>4)*4 + reg
    const int cn  = lane & 15;
    const int cr4 = (lane >> 4) * 4;
    #pragma unroll
    for (int i = 0; i < 4; ++i)
        #pragma unroll
        for (int j = 0; j < 4; ++j)
            #pragma unroll
            for (int r = 0; r < 4; ++r) {
                const int row = bm + wm + i * 16 + cr4 + r;
                const int col = bn + wn + j * 16 + cn;
                float v = acc[i][j][r];
                if (EPI == 1) {
                    v += bias[col];
                    v = fmaxf(v, 0.f) + log1pf(__expf(-fabsf(v)));  // stable softplus
                }
                C[(long)row * ldc + col] = v;
            }
}

// ---------------------------------------------------------------------------
// x_dbl split-K MFMA GEMM, single-pass K (R10): A = xcS (8192 x 3072 split),
// B = W_xS (128-row padded, 80 valid), K=1536 -> 48 k-tiles split 4 ways.
// grid(4, 64); partials to Pout[s][8192][128].
// ---------------------------------------------------------------------------
__global__ __launch_bounds__(256)
void gemm_xdbl(const __bf16* __restrict__ A, const __bf16* __restrict__ B,
               float* __restrict__ Pout)
{
    __shared__ __bf16 Asl[128 * 64];
    __shared__ __bf16 Bsl[128 * 64];

    const int tid  = threadIdx.x;
    const int lane = tid & 63;
    const int w    = tid >> 6;
    const int wm   = (w >> 1) * 64;
    const int wn   = (w & 1) * 64;

    const int s  = blockIdx.x;           // split-K index 0..3
    const int bm = blockIdx.y * 128;
    const int K  = 1536;
    const long lda = 3072, ldb = 3072;

    f32x4 acc[4][4];
    #pragma unroll
    for (int i = 0; i < 4; ++i)
        #pragma unroll
        for (int j = 0; j < 4; ++j)
            acc[i][j] = (f32x4){0.f, 0.f, 0.f, 0.f};

    const int srow = w * 32 + (lane >> 3);
    const int q    = (lane & 7) ^ ((lane >> 3) & 7);
    const int qoff = (q < 4) ? q * 8 : K + (q - 4) * 8;
    const __bf16* Abase = A + (long)(bm + srow) * lda + qoff;
    const __bf16* Bbase = B + (long)srow * ldb + qoff;
    char* AslW = (char*)Asl + (w * 32) * 128;
    char* BslW = (char*)Bsl + (w * 32) * 128;

    const int fr = lane & 15;
    const int g4 = lane >> 4;
    const long lda8 = 8 * lda, ldb8 = 8 * ldb;

    for (int kt = s * 12; kt < (s + 1) * 12; ++kt) {
        const int kk = kt * 32;
        __syncthreads();
        #pragma unroll
        for (int j = 0; j < 4; ++j) {
            async_copy16(Abase + j * lda8 + kk, AslW + j * 1024);
            async_copy16(Bbase + j * ldb8 + kk, BslW + j * 1024);
        }
        __syncthreads();

        bf16x8 ah[4], al[4], bh[4], bl[4];
        #pragma unroll
        for (int t = 0; t < 4; ++t) {
            const int ra = wm + t * 16 + fr;
            const int rb = wn + t * 16 + fr;
            ah[t] = *(const bf16x8*)&Asl[ra * 64 + ((g4       ^ (ra & 7)) * 8)];
            al[t] = *(const bf16x8*)&Asl[ra * 64 + (((4 + g4) ^ (ra & 7)) * 8)];
            bh[t] = *(const bf16x8*)&Bsl[rb * 64 + ((g4       ^ (rb & 7)) * 8)];
            bl[t] = *(const bf16x8*)&Bsl[rb * 64 + (((4 + g4) ^ (rb & 7)) * 8)];
        }
        #pragma unroll
        for (int i = 0; i < 4; ++i)
            #pragma unroll
            for (int j = 0; j < 4; ++j) {
                acc[i][j] = __builtin_amdgcn_mfma_f32_16x16x32_bf16(ah[i], bh[j], acc[i][j], 0, 0, 0);
                acc[i][j] = __builtin_amdgcn_mfma_f32_16x16x32_bf16(ah[i], bl[j], acc[i][j], 0, 0, 0);
                acc[i][j] = __builtin_amdgcn_mfma_f32_16x16x32_bf16(al[i], bh[j], acc[i][j], 0, 0, 0);
            }
    }

    float* Cp = Pout + (long)s * (8192L * 128);
    const int cn  = lane & 15;
    const int cr4 = (lane >> 4) * 4;
    #pragma unroll
    for (int i = 0; i < 4; ++i)
        #pragma unroll
        for (int j = 0; j < 4; ++j)
            #pragma unroll
            for (int r = 0; r < 4; ++r) {
                const int row = bm + wm + i * 16 + cr4 + r;
                const int col = wn + j * 16 + cn;
                Cp[(long)row * 128 + col] = acc[i][j][r];
            }
}

// ---------------------------------------------------------------------------
// Reduce 4 split-K partials into (a) xbc (8192 x 32, B/C cols 48..79) and
// (b) xdtS (8192 x 128 padded split: hi of k 0..47 at cols 0..47, lo at
// 64..111, zero pads) — the dt-GEMM A operand.
// ---------------------------------------------------------------------------
__global__ __launch_bounds__(256)
void xdbl_reduce3(const float* __restrict__ Pout, float* __restrict__ xbc,
                  __bf16* __restrict__ xdtS)
{
    const long i = (long)blockIdx.x * 256 + threadIdx.x;   // over 8192*128
    if (i >= 8192L * 128) return;
    const long r  = i >> 7;
    const int  c  = (int)(i & 127);
    const long st = 8192L * 128;
    const long rb = r * 128;

    const int k = c & 63;
    float u = 0.f;
    if (k < 48) {
        const long o = rb + k;
        u = (Pout[o] + Pout[o + st]) + (Pout[o + 2 * st] + Pout[o + 3 * st]);
    }
    const __bf16 hi = (__bf16)u;
    xdtS[rb + c] = (c < 64) ? hi : (__bf16)(u - (float)hi);

    if (c >= 96) {                      // cols 96..127 also emit xbc 0..31
        const int j = c - 96;
        const long o = rb + 48 + j;
        xbc[r * 32 + j] =
            (Pout[o] + Pout[o + st]) + (Pout[o + 2 * st] + Pout[o + 3 * st]);
    }
}

// ---------------------------------------------------------------------------
// Merged input/weight split: x, W_in, W_out, W_x, W_dt (padded 1536x128).
// ---------------------------------------------------------------------------
#define NW0 ((long)BL * 768)
#define NW1 (3072L * 768)
#define NW2 (768L * 1536)
#define NW3 (80L * 1536)
#define NW4 (1536L * 128)
__global__ __launch_bounds__(256)
void split_all(const float* __restrict__ x,
               const float* __restrict__ W_in, const float* __restrict__ W_out,
               const float* __restrict__ W_x, const float* __restrict__ W_dt,
               __bf16* __restrict__ xS,
               __bf16* __restrict__ wInS, __bf16* __restrict__ wOutS,
               __bf16* __restrict__ wXS, __bf16* __restrict__ wDtS)
{
    long i = (long)blockIdx.x * 256 + threadIdx.x;
    if (i < NW0) {
        const long row = i / 768; const int col = (int)(i - row * 768);
        const float a = x[i];
        const __bf16 h = (__bf16)a;
        __bf16* d = xS + row * 1536 + col;
        d[0] = h; d[768] = (__bf16)(a - (float)h);
        return;
    }
    i -= NW0;
    if (i < NW1) {
        const long row = i / 768; const int col = (int)(i - row * 768);
        const float a = W_in[i];
        const __bf16 h = (__bf16)a;
        __bf16* d = wInS + row * 1536 + col;
        d[0] = h; d[768] = (__bf16)(a - (float)h);
        return;
    }
    i -= NW1;
    if (i < NW2) {
        const long row = i / 1536; const int col = (int)(i - row * 1536);
        const float a = W_out[i];
        const __bf16 h = (__bf16)a;
        __bf16* d = wOutS + row * 3072 + col;
        d[0] = h; d[1536] = (__bf16)(a - (float)h);
        return;
    }
    i -= NW2;
    if (i < NW3) {
        const long row = i / 1536; const int col = (int)(i - row * 1536);
        const float a = W_x[i];
        const __bf16 h = (__bf16)a;
        __bf16* d = wXS + row * 3072 + col;
        d[0] = h; d[1536] = (__bf16)(a - (float)h);
        return;
    }
    i -= NW3;
    if (i < NW4) {
        const long row = i >> 7; const int c = (int)(i & 127);
        const int k = c & 63;
        const float a = (k < 48) ? W_dt[row * 48 + k] : 0.f;
        const __bf16 h = (__bf16)a;
        wDtS[row * 128 + c] = (c < 64) ? h : (__bf16)(a - (float)h);
    }
}

// ---------------------------------------------------------------------------
// Depthwise causal conv (width 4) + bias + SiLU -> xcS split-bf16.
// ---------------------------------------------------------------------------
__global__ __launch_bounds__(256)
void conv_silu_kernel(const float* __restrict__ xz,
                      const float* __restrict__ conv_w,
                      const float* __restrict__ conv_b,
                      __bf16* __restrict__ xcS)
{
    const long idx = (long)blockIdx.x * 256 + threadIdx.x;
    const int d  = (int)(idx % D_INNER);
    const long bl = idx / D_INNER;
    const int l  = (int)(bl % SEQ_LEN);

    const float w0 = conv_w[d * 4 + 0];
    const float w1 = conv_w[d * 4 + 1];
    const float w2 = conv_w[d * 4 + 2];
    const float w3 = conv_w[d * 4 + 3];

    const float* base = xz + bl * 3072 + d;
    float s = conv_b[d];
    if (l >= 3) s = fmaf(base[-3 * 3072], w0, s);
    if (l >= 2) s = fmaf(base[-2 * 3072], w1, s);
    if (l >= 1) s = fmaf(base[-1 * 3072], w2, s);
    s = fmaf(base[0], w3, s);
    const float sig = 1.f / (1.f + __expf(-s));
    const float v = s * sig;
    const __bf16 hi = (__bf16)v;
    const __bf16 lo = (__bf16)(v - (float)hi);
    xcS[bl * 3072 + d]        = hi;
    xcS[bl * 3072 + 1536 + d] = lo;
}

// ---------------------------------------------------------------------------
// Scan phase A: per (b, d, chunk): P = prod(a_l), S = local scan (h0=0).
// B/C from xbc (8192 x 32: B_t = [0:16], C_t = [16:32]).
// ---------------------------------------------------------------------------
__global__ __launch_bounds__(256)
void scan_phaseA(const __bf16* __restrict__ xcS, const float* __restrict__ xz,
                 const float* __restrict__ xbc, const float* __restrict__ A_log,
                 float* __restrict__ P, float* __restrict__ S)
{
    const int d = blockIdx.x * 256 + threadIdx.x;
    const int c = blockIdx.y;
    const int b = blockIdx.z;

    float An[16], Pr[16], Sr[16];
    #pragma unroll
    for (int n = 0; n < 16; ++n) {
        An[n] = -__expf(A_log[d * 16 + n]);
        Pr[n] = 1.f;
        Sr[n] = 0.f;
    }

    const long bl0 = (long)b * SEQ_LEN + (long)c * CHUNK;
    for (int l = 0; l < CHUNK; ++l) {
        const long bl = bl0 + l;
        const float dt  = xz[bl * 3072 + d];
        const float x   = (float)xcS[bl * 3072 + d] + (float)xcS[bl * 3072 + 1536 + d];
        const float dtx = dt * x;
        const float* bc = xbc + bl * 32;
        #pragma unroll
        for (int n = 0; n < 16; ++n) {
            const float a = __expf(dt * An[n]);
            Pr[n] *= a;
            Sr[n] = fmaf(a, Sr[n], dtx * bc[n]);
        }
    }

    const long base = ((long)(b * NCHUNK + c) * 16) * D_INNER + d;
    #pragma unroll
    for (int n = 0; n < 16; ++n) {
        P[base + (long)n * D_INNER] = Pr[n];
        S[base + (long)n * D_INNER] = Sr[n];
    }
}

// ---------------------------------------------------------------------------
// Scan phase B: one thread per (b, n, d) — 384 blocks, coalesced over d.
// ---------------------------------------------------------------------------
__global__ __launch_bounds__(256)
void scan_phaseB(const float* __restrict__ P, const float* __restrict__ S,
                 float* __restrict__ H)
{
    const int t = blockIdx.x * 256 + threadIdx.x;   // over BATCH*16*D_INNER
    const int d = t % D_INNER;
    const int r = t / D_INNER;
    const int n = r & 15;
    const int b = r >> 4;

    float h = 0.f;
    for (int c = 0; c < NCHUNK; ++c) {
        const long i = ((long)(b * NCHUNK + c) * 16 + n) * D_INNER + d;
        H[i] = h;
        h = fmaf(P[i], h, S[i]);
    }
}

// ---------------------------------------------------------------------------
// Scan phase C: re-run chunks from h_in, emit y, gate with silu(z), write
// split-bf16 in-place over xcS -> yS.
// ---------------------------------------------------------------------------
__global__ __launch_bounds__(256)
void scan_phaseC(__bf16* xcS_yS, const float* __restrict__ xz,
                 const float* __restrict__ xbc, const float* __restrict__ A_log,
                 const float* __restrict__ Dp, const float* __restrict__ H)
{
    const int d = blockIdx.x * 256 + threadIdx.x;
    const int c = blockIdx.y;
    const int b = blockIdx.z;

    float An[16], h[16];
    const long hbase = ((long)(b * NCHUNK + c) * 16) * D_INNER + d;
    #pragma unroll
    for (int n = 0; n < 16; ++n) {
        An[n] = -__expf(A_log[d * 16 + n]);
        h[n]  = H[hbase + (long)n * D_INNER];
    }
    const float Dd = Dp[d];

    const long bl0 = (long)b * SEQ_LEN + (long)c * CHUNK;
    for (int l = 0; l < CHUNK; ++l) {
        const long bl = bl0 + l;
        const float dt  = xz[bl * 3072 + d];
        const float x   = (float)xcS_yS[bl * 3072 + d] + (float)xcS_yS[bl * 3072 + 1536 + d];
        const float dtx = dt * x;
        const float* bc = xbc + bl * 32;
        float y = Dd * x;
        #pragma unroll
        for (int n = 0; n < 16; ++n) {
            const float a = __expf(dt * An[n]);
            h[n] = fmaf(a, h[n], dtx * bc[n]);
            y = fmaf(h[n], bc[16 + n], y);
        }
        const float z  = xz[bl * 3072 + D_INNER + d];
        const float sz = z / (1.f + __expf(-z));
        const float v  = y * sz;
        const __bf16 hi = (__bf16)v;
        const __bf16 lo = (__bf16)(v - (float)hi);
        xcS_yS[bl * 3072 + d]        = hi;
        xcS_yS[bl * 3072 + 1536 + d] = lo;
    }
}

// ---------------------------------------------------------------------------
extern "C" void kernel_launch(void* const* d_in, const int* in_sizes, int n_in,
                              void* d_out, int out_size, void* d_ws, size_t ws_size,
                              hipStream_t stream)
{
    const float* x      = (const float*)d_in[0];   // (4,2048,768)
    const float* W_in   = (const float*)d_in[1];   // (3072,768)
    const float* conv_w = (const float*)d_in[2];   // (1536,1,4)
    const float* conv_b = (const float*)d_in[3];   // (1536,)
    const float* W_x    = (const float*)d_in[4];   // (80,1536)
    const float* W_dt   = (const float*)d_in[5];   // (1536,48)
    const float* b_dt   = (const float*)d_in[6];   // (1536,)
    const float* A_log  = (const float*)d_in[7];   // (1536,16)
    const float* D_p    = (const float*)d_in[8];   // (1536,)
    const float* W_out  = (const float*)d_in[9];   // (768,1536)
    float* out = (float*)d_out;                    // (4,2048,768)

    // ---- workspace carve, ~202 MB ---------------------------------------
    char* p = (char*)d_ws;
    auto take = [&](size_t bytes) { char* r = p; p += (bytes + 255) & ~(size_t)255; return r; };

    float*  xz    = (float*)take((size_t)BL * 3072 * 4);    // 100.7 MB (dt | z)
    float*  H     = (float*)take((size_t)BATCH * NCHUNK * 16 * D_INNER * 4); // 12.6 MB
    __bf16* wOutS = (__bf16*)take(768L * 3072 * 2);         //   4.7 MB
    __bf16* wXS   = (__bf16*)take(128L * 3072 * 2);         //   0.8 MB (80 valid)
    __bf16* wDtS  = (__bf16*)take(1536L * 128 * 2);         //   0.4 MB
    __bf16* xdtS  = (__bf16*)take(8192L * 128 * 2);         //   2.1 MB
    float*  xbc   = (float*)take(8192L * 32 * 4);           //   1.0 MB
    float*  Pout  = (float*)take(4L * 8192 * 128 * 4);      //  16.8 MB (-> P overlay)
    float*  S     = (float*)take((size_t)BATCH * NCHUNK * 16 * D_INNER * 4); // 12.6 MB
    float*  P     = Pout;   // Pout dead after xdbl_reduce3; P needs 12.6 MB

    // REGION (50.4 MB), time-multiplexed:
    //   phase 1:   xS (25.2MB) + wInS (9.4MB)
    //   phase 2-8: xcS (8192x3072 bf16), phaseC overwrites in-place -> yS
    char* region = take(50331648);
    __bf16* xS   = (__bf16*)region;
    __bf16* wInS = (__bf16*)(region + 25165824);
    __bf16* xcS  = (__bf16*)region;
    __bf16* yS   = (__bf16*)region;

    // 0) split conversions (x + weights, one launch)
    {
        const long n = NW0 + NW1 + NW2 + NW3 + NW4;
        split_all<<<(int)((n + 255) / 256), 256, 0, stream>>>(
            x, W_in, W_out, W_x, W_dt, xS, wInS, wOutS, wXS, wDtS);
    }
    // 1) xz = x @ W_in^T  (256x256 single-buffered co-resident MFMA, K=768)
    {
        dim3 grid(3072 / 256, BL / 256);   // 12 x 32 = 384 blocks, 2/CU
        gemm256<<<grid, 512, 0, stream>>>(xS, wInS, xz, 768, 3072);
    }
    // 2) conv + bias + SiLU -> xcS (overlays xS)
    {
        const long total = (long)BL * D_INNER;
        conv_silu_kernel<<<(int)(total / 256), 256, 0, stream>>>(xz, conv_w, conv_b, xcS);
    }
    // 3) x_dbl split-K MFMA -> Pout
    {
        dim3 grid(4, BL / 128);
        gemm_xdbl<<<grid, 256, 0, stream>>>(xcS, wXS, Pout);
    }
    // 4) reduce partials -> xbc + xdtS
    {
        const long n = 8192L * 128;
        xdbl_reduce3<<<(int)((n + 255) / 256), 256, 0, stream>>>(Pout, xbc, xdtS);
    }
    // 5) dt = softplus(xdt @ W_dt^T + b_dt)  (R10 MFMA, K=64 padded)
    {
        dim3 grid(1536 / 128, BL / 128);
        gemm_f<1><<<grid, 256, 0, stream>>>(xdtS, wDtS, xz, b_dt,
                                            BL, 1536, 64, 3072);
    }
    // 6) scan phase A  (P overlays dead Pout)
    {
        dim3 grid(D_INNER / 256, NCHUNK, BATCH);
        scan_phaseA<<<grid, 256, 0, stream>>>(xcS, xz, xbc, A_log, P, S);
    }
    // 7) scan phase B (per-(b,n,d): 384 blocks)
    scan_phaseB<<<(BATCH * 16 * D_INNER) / 256, 256, 0, stream>>>(P, S, H);
    // 8) scan phase C: xcS -> yS in-place
    {
        dim3 grid(D_INNER / 256, NCHUNK, BATCH);
        scan_phaseC<<<grid, 256, 0, stream>>>(xcS, xz, xbc, A_log, D_p, H);
    }
    // 9) out = y @ W_out^T  (R10 MFMA, M=8192, N=768, K=1536)
    {
        dim3 grid(768 / 128, BL / 128);
        gemm_f<0><<<grid, 256, 0, stream>>>(yS, wOutS, out, nullptr,
                                            BL, 768, 1536, 768);
    }
}

// Round 8
// 523.943 us; speedup vs baseline: 2.4950x; 1.1105x over previous
//
#include <hip/hip_runtime.h>
#include <hip/hip_bf16.h>
#include <math.h>

// Problem constants (fixed by reference)
#define D_MODEL   768
#define D_STATE   16
#define D_CONV    4
#define D_INNER   1536
#define DT_RANK   48
#define BATCH     4
#define SEQ_LEN   2048
#define BL        (BATCH * SEQ_LEN)        // 8192 rows
#define NCHUNK    32
#define CHUNK     (SEQ_LEN / NCHUNK)       // 64

typedef __bf16 bf16x8 __attribute__((ext_vector_type(8)));
typedef float  f32x4  __attribute__((ext_vector_type(4)));

__device__ __forceinline__ void async_copy16(const void* g, void* l) {
    __builtin_amdgcn_global_load_lds(
        (const __attribute__((address_space(1))) void*)g,
        (__attribute__((address_space(3))) void*)l,
        16, 0, 0);
}

// ===========================================================================
// Step-1 kernel: R15 verbatim (best verified: 118 us, 41% MfmaUtil).
// 256x256 tile, 8 waves, 4-phase pipelined K-loop, relaxed counted vmcnt.
// Stage issue order matches next-tile consume order (A0'@ph1, B0'@ph2,
// B1'@ph3, A1'@ph4); vmcnt(6) at ph1-ph3, barrier-only at ph4.
// Race-safety: phase (ih,jh) reads only stage units (A_ih,B_jh) (R14 remap).
// LDS: 2 x (32KB A + 32KB B) = 128 KB.  Swizzle = R8 (0 conflicts).
// ===========================================================================

#define SYNC_V6 do { asm volatile("s_waitcnt vmcnt(6)" ::: "memory"); \
    __builtin_amdgcn_s_barrier(); __builtin_amdgcn_sched_barrier(0); } while (0)
#define SYNC_V4 do { asm volatile("s_waitcnt vmcnt(4)" ::: "memory"); \
    __builtin_amdgcn_s_barrier(); __builtin_amdgcn_sched_barrier(0); } while (0)
#define SYNC_V2 do { asm volatile("s_waitcnt vmcnt(2)" ::: "memory"); \
    __builtin_amdgcn_s_barrier(); __builtin_amdgcn_sched_barrier(0); } while (0)
#define SYNC_V0 do { asm volatile("s_waitcnt vmcnt(0)" ::: "memory"); \
    __builtin_amdgcn_s_barrier(); __builtin_amdgcn_sched_barrier(0); } while (0)
#define SYNC_B  do { \
    __builtin_amdgcn_s_barrier(); __builtin_amdgcn_sched_barrier(0); } while (0)

template<int IH, int JH>
__device__ __forceinline__ void quad24(f32x4 (&acc)[2][4][2][2],
                                       const bf16x8 (&aH)[4], const bf16x8 (&aL)[4],
                                       const bf16x8 (&bH)[2], const bf16x8 (&bL)[2])
{
    __builtin_amdgcn_s_setprio(1);
    #pragma unroll
    for (int i = 0; i < 4; ++i)
        #pragma unroll
        for (int j = 0; j < 2; ++j) {
            acc[IH][i][JH][j] = __builtin_amdgcn_mfma_f32_16x16x32_bf16(aH[i], bH[j], acc[IH][i][JH][j], 0, 0, 0);
            acc[IH][i][JH][j] = __builtin_amdgcn_mfma_f32_16x16x32_bf16(aH[i], bL[j], acc[IH][i][JH][j], 0, 0, 0);
            acc[IH][i][JH][j] = __builtin_amdgcn_mfma_f32_16x16x32_bf16(aL[i], bH[j], acc[IH][i][JH][j], 0, 0, 0);
        }
    __builtin_amdgcn_s_setprio(0);
}

__global__ __launch_bounds__(512, 2)
void gemm256(const __bf16* __restrict__ A, const __bf16* __restrict__ B,
             float* __restrict__ C, int K, int ldc)
{
    __shared__ __bf16 Asl0[256 * 64];
    __shared__ __bf16 Bsl0[256 * 64];
    __shared__ __bf16 Asl1[256 * 64];
    __shared__ __bf16 Bsl1[256 * 64];

    const int tid  = threadIdx.x;
    const int lane = tid & 63;
    const int w    = tid >> 6;          // 0..7
    const int aw   = (w >> 2) * 64;     // A sub-slice within each 128-row half
    const int bw   = (w & 3) * 32;      // B sub-slice within each 128-row half

    const int bm = blockIdx.y * 256;
    const int bn = blockIdx.x * 256;

    const long lda = 2L * K;
    const long ldb = 2L * K;

    f32x4 acc[2][4][2][2];
    #pragma unroll
    for (int a = 0; a < 2; ++a)
        #pragma unroll
        for (int i = 0; i < 4; ++i)
            #pragma unroll
            for (int b = 0; b < 2; ++b)
                #pragma unroll
                for (int j = 0; j < 2; ++j)
                    acc[a][i][b][j] = (f32x4){0.f, 0.f, 0.f, 0.f};

    const int srow = w * 8 + (lane >> 3);
    const int q    = (lane & 7) ^ ((lane >> 3) & 7);
    const int qoff = (q < 4) ? q * 8 : K + (q - 4) * 8;
    const __bf16* Ab = A + (long)(bm + srow) * lda + qoff;
    const __bf16* Bb = B + (long)(bn + srow) * ldb + qoff;
    const long lda64 = 64 * lda, ldb64 = 64 * ldb;
    const int wo = w * 1024;            // wave's 8-row slice within a call

    const int fr = lane & 15;
    const int g4 = lane >> 4;           // k-chunk group 0..3 within 32-k tile

    const int nt = K >> 5;              // 32-k tiles, nt >= 2

    __bf16 *Ac = Asl0, *Bc = Bsl0, *An = Asl1, *Bn = Bsl1;

    auto stA = [&](int kk, __bf16* dst, int half) {
        char* d = (char*)dst + half * 16384 + wo;
        const __bf16* s = Ab + kk + (long)(2 * half) * lda64;
        async_copy16(s, d);
        async_copy16(s + lda64, d + 8192);
    };
    auto stB = [&](int kk, __bf16* dst, int half) {
        char* d = (char*)dst + half * 16384 + wo;
        const __bf16* s = Bb + kk + (long)(2 * half) * ldb64;
        async_copy16(s, d);
        async_copy16(s + ldb64, d + 8192);
    };
    auto rdA = [&](const __bf16* As, int ih, bf16x8 (&aH)[4], bf16x8 (&aL)[4]) {
        #pragma unroll
        for (int t = 0; t < 4; ++t) {
            const int ra = aw + ih * 128 + t * 16 + fr;
            aH[t] = *(const bf16x8*)&As[ra * 64 + ((g4       ^ (ra & 7)) * 8)];
            aL[t] = *(const bf16x8*)&As[ra * 64 + (((4 + g4) ^ (ra & 7)) * 8)];
        }
    };
    auto rdB = [&](const __bf16* Bs, int jh, bf16x8 (&bH)[2], bf16x8 (&bL)[2]) {
        #pragma unroll
        for (int t = 0; t < 2; ++t) {
            const int rb = bw + jh * 128 + t * 16 + fr;
            bH[t] = *(const bf16x8*)&Bs[rb * 64 + ((g4       ^ (rb & 7)) * 8)];
            bL[t] = *(const bf16x8*)&Bs[rb * 64 + (((4 + g4) ^ (rb & 7)) * 8)];
        }
    };

    // prologue: tile 0 units in consume order [A0, B0, B1, A1]
    stA(0, Ac, 0);
    stB(0, Bc, 0);
    stB(0, Bc, 1);
    stA(0, Ac, 1);
    SYNC_V4;

    for (int t = 0; t < nt - 1; ++t) {
        const int kk1 = (t + 1) * 32;
        bf16x8 aH[4], aL[4], bH[2], bL[2];
        // ph1 (0,0): reads A0,B0; stage A0(t+1)
        rdA(Ac, 0, aH, aL);
        rdB(Bc, 0, bH, bL);
        stA(kk1, An, 0);
        SYNC_V6;
        quad24<0, 0>(acc, aH, aL, bH, bL);
        // ph2 (0,1): reads B1; stage B0(t+1)
        rdB(Bc, 1, bH, bL);
        stB(kk1, Bn, 0);
        SYNC_V6;
        quad24<0, 1>(acc, aH, aL, bH, bL);
        // ph3 (1,1): reads A1; stage B1(t+1)
        rdA(Ac, 1, aH, aL);
        stB(kk1, Bn, 1);
        SYNC_V6;
        quad24<1, 1>(acc, aH, aL, bH, bL);
        // ph4 (1,0): re-reads B0; stage A1(t+1)
        rdB(Bc, 0, bH, bL);
        stA(kk1, An, 1);
        SYNC_B;
        quad24<1, 0>(acc, aH, aL, bH, bL);
        __bf16* tp;
        tp = Ac; Ac = An; An = tp;
        tp = Bc; Bc = Bn; Bn = tp;
    }

    // peeled last tile: drain 4 -> 2 -> 0
    {
        bf16x8 aH[4], aL[4], bH[2], bL[2];
        rdA(Ac, 0, aH, aL);
        rdB(Bc, 0, bH, bL);
        SYNC_V4;
        quad24<0, 0>(acc, aH, aL, bH, bL);
        rdB(Bc, 1, bH, bL);
        SYNC_V2;
        quad24<0, 1>(acc, aH, aL, bH, bL);
        rdA(Ac, 1, aH, aL);
        SYNC_V0;
        quad24<1, 1>(acc, aH, aL, bH, bL);
        rdB(Bc, 0, bH, bL);
        quad24<1, 0>(acc, aH, aL, bH, bL);
    }

    // C/D layout (m89-verified): col = lane&15, row = (lane>>4)*4 + reg
    const int cn  = lane & 15;
    const int cr4 = (lane >> 4) * 4;
    #pragma unroll
    for (int ih = 0; ih < 2; ++ih)
        #pragma unroll
        for (int i = 0; i < 4; ++i)
            #pragma unroll
            for (int jh = 0; jh < 2; ++jh)
                #pragma unroll
                for (int j = 0; j < 2; ++j)
                    #pragma unroll
                    for (int r = 0; r < 4; ++r) {
                        const int row = bm + aw + ih * 128 + i * 16 + cr4 + r;
                        const int col = bn + bw + jh * 128 + j * 16 + cn;
                        C[(long)row * ldc + col] = acc[ih][i][jh][j][r];
                    }
}

// ---------------------------------------------------------------------------
// Split-bf16 MFMA GEMM (NT), SINGLE-PASS K (R10 — known-good).  128x128 tile,
// 4 waves of 64x64.  EPI 0: plain store.  EPI 1: softplus(v + bias[col]).
// ---------------------------------------------------------------------------
template <int EPI>
__global__ __launch_bounds__(256)
void gemm_f(const __bf16* __restrict__ A, const __bf16* __restrict__ B,
            float* __restrict__ C, const float* __restrict__ bias,
            int M, int N, int K, int ldc)
{
    __shared__ __bf16 Asl[128 * 64];
    __shared__ __bf16 Bsl[128 * 64];

    const int tid  = threadIdx.x;
    const int lane = tid & 63;
    const int w    = tid >> 6;
    const int wm   = (w >> 1) * 64;
    const int wn   = (w & 1) * 64;

    const int bm = blockIdx.y * 128;
    const int bn = blockIdx.x * 128;

    const long lda = 2L * K;
    const long ldb = 2L * K;

    f32x4 acc[4][4];
    #pragma unroll
    for (int i = 0; i < 4; ++i)
        #pragma unroll
        for (int j = 0; j < 4; ++j)
            acc[i][j] = (f32x4){0.f, 0.f, 0.f, 0.f};

    const int srow = w * 32 + (lane >> 3);
    const int q    = (lane & 7) ^ ((lane >> 3) & 7);
    const int qoff = (q < 4) ? q * 8 : K + (q - 4) * 8;
    const __bf16* Abase = A + (long)(bm + srow) * lda + qoff;
    const __bf16* Bbase = B + (long)(bn + srow) * ldb + qoff;
    char* AslW = (char*)Asl + (w * 32) * 128;
    char* BslW = (char*)Bsl + (w * 32) * 128;

    const int fr = lane & 15;
    const int g4 = lane >> 4;          // k-chunk group 0..3 within 32-k tile
    const long lda8 = 8 * lda, ldb8 = 8 * ldb;

    for (int kk = 0; kk < K; kk += 32) {
        __syncthreads();
        #pragma unroll
        for (int j = 0; j < 4; ++j) {
            async_copy16(Abase + j * lda8 + kk, AslW + j * 1024);
            async_copy16(Bbase + j * ldb8 + kk, BslW + j * 1024);
        }
        __syncthreads();

        bf16x8 ah[4], al[4], bh[4], bl[4];
        #pragma unroll
        for (int t = 0; t < 4; ++t) {
            const int ra = wm + t * 16 + fr;
            const int rb = wn + t * 16 + fr;
            ah[t] = *(const bf16x8*)&Asl[ra * 64 + ((g4       ^ (ra & 7)) * 8)];
            al[t] = *(const bf16x8*)&Asl[ra * 64 + (((4 + g4) ^ (ra & 7)) * 8)];
            bh[t] = *(const bf16x8*)&Bsl[rb * 64 + ((g4       ^ (rb & 7)) * 8)];
            bl[t] = *(const bf16x8*)&Bsl[rb * 64 + (((4 + g4) ^ (rb & 7)) * 8)];
        }
        #pragma unroll
        for (int i = 0; i < 4; ++i)
            #pragma unroll
            for (int j = 0; j < 4; ++j) {
                acc[i][j] = __builtin_amdgcn_mfma_f32_16x16x32_bf16(ah[i], bh[j], acc[i][j], 0, 0, 0);
                acc[i][j] = __builtin_amdgcn_mfma_f32_16x16x32_bf16(ah[i], bl[j], acc[i][j], 0, 0, 0);
                acc[i][j] = __builtin_amdgcn_mfma_f32_16x16x32_bf16(al[i], bh[j], acc[i][j], 0, 0, 0);
            }
    }

    // C/D layout (m89-verified): col = lane&15, row = (lane>>4)*4 + reg
    const int cn  = lane & 15;
    const int cr4 = (lane >> 4) * 4;
    #pragma unroll
    for (int i = 0; i < 4; ++i)
        #pragma unroll
        for (int j = 0; j < 4; ++j)
            #pragma unroll
            for (int r = 0; r < 4; ++r) {
                const int row = bm + wm + i * 16 + cr4 + r;
                const int col = bn + wn + j * 16 + cn;
                float v = acc[i][j][r];
                if (EPI == 1) {
                    v += bias[col];
                    v = fmaxf(v, 0.f) + log1pf(__expf(-fabsf(v)));  // stable softplus
                }
                C[(long)row * ldc + col] = v;
            }
}

// ---------------------------------------------------------------------------
// x_dbl split-K MFMA GEMM, single-pass K (R10): A = xcS (8192 x 3072 split),
// B = W_xS (128-row padded, 80 valid), K=1536 -> 48 k-tiles split 4 ways.
// ---------------------------------------------------------------------------
__global__ __launch_bounds__(256)
void gemm_xdbl(const __bf16* __restrict__ A, const __bf16* __restrict__ B,
               float* __restrict__ Pout)
{
    __shared__ __bf16 Asl[128 * 64];
    __shared__ __bf16 Bsl[128 * 64];

    const int tid  = threadIdx.x;
    const int lane = tid & 63;
    const int w    = tid >> 6;
    const int wm   = (w >> 1) * 64;
    const int wn   = (w & 1) * 64;

    const int s  = blockIdx.x;           // split-K index 0..3
    const int bm = blockIdx.y * 128;
    const int K  = 1536;
    const long lda = 3072, ldb = 3072;

    f32x4 acc[4][4];
    #pragma unroll
    for (int i = 0; i < 4; ++i)
        #pragma unroll
        for (int j = 0; j < 4; ++j)
            acc[i][j] = (f32x4){0.f, 0.f, 0.f, 0.f};

    const int srow = w * 32 + (lane >> 3);
    const int q    = (lane & 7) ^ ((lane >> 3) & 7);
    const int qoff = (q < 4) ? q * 8 : K + (q - 4) * 8;
    const __bf16* Abase = A + (long)(bm + srow) * lda + qoff;
    const __bf16* Bbase = B + (long)srow * ldb + qoff;
    char* AslW = (char*)Asl + (w * 32) * 128;
    char* BslW = (char*)Bsl + (w * 32) * 128;

    const int fr = lane & 15;
    const int g4 = lane >> 4;
    const long lda8 = 8 * lda, ldb8 = 8 * ldb;

    for (int kt = s * 12; kt < (s + 1) * 12; ++kt) {
        const int kk = kt * 32;
        __syncthreads();
        #pragma unroll
        for (int j = 0; j < 4; ++j) {
            async_copy16(Abase + j * lda8 + kk, AslW + j * 1024);
            async_copy16(Bbase + j * ldb8 + kk, BslW + j * 1024);
        }
        __syncthreads();

        bf16x8 ah[4], al[4], bh[4], bl[4];
        #pragma unroll
        for (int t = 0; t < 4; ++t) {
            const int ra = wm + t * 16 + fr;
            const int rb = wn + t * 16 + fr;
            ah[t] = *(const bf16x8*)&Asl[ra * 64 + ((g4       ^ (ra & 7)) * 8)];
            al[t] = *(const bf16x8*)&Asl[ra * 64 + (((4 + g4) ^ (ra & 7)) * 8)];
            bh[t] = *(const bf16x8*)&Bsl[rb * 64 + ((g4       ^ (rb & 7)) * 8)];
            bl[t] = *(const bf16x8*)&Bsl[rb * 64 + (((4 + g4) ^ (rb & 7)) * 8)];
        }
        #pragma unroll
        for (int i = 0; i < 4; ++i)
            #pragma unroll
            for (int j = 0; j < 4; ++j) {
                acc[i][j] = __builtin_amdgcn_mfma_f32_16x16x32_bf16(ah[i], bh[j], acc[i][j], 0, 0, 0);
                acc[i][j] = __builtin_amdgcn_mfma_f32_16x16x32_bf16(ah[i], bl[j], acc[i][j], 0, 0, 0);
                acc[i][j] = __builtin_amdgcn_mfma_f32_16x16x32_bf16(al[i], bh[j], acc[i][j], 0, 0, 0);
            }
    }

    float* Cp = Pout + (long)s * (8192L * 128);
    const int cn  = lane & 15;
    const int cr4 = (lane >> 4) * 4;
    #pragma unroll
    for (int i = 0; i < 4; ++i)
        #pragma unroll
        for (int j = 0; j < 4; ++j)
            #pragma unroll
            for (int r = 0; r < 4; ++r) {
                const int row = bm + wm + i * 16 + cr4 + r;
                const int col = wn + j * 16 + cn;
                Cp[(long)row * 128 + col] = acc[i][j][r];
            }
}

// ---------------------------------------------------------------------------
// Reduce 4 split-K partials -> xbc + xdtS.
// ---------------------------------------------------------------------------
__global__ __launch_bounds__(256)
void xdbl_reduce3(const float* __restrict__ Pout, float* __restrict__ xbc,
                  __bf16* __restrict__ xdtS)
{
    const long i = (long)blockIdx.x * 256 + threadIdx.x;   // over 8192*128
    if (i >= 8192L * 128) return;
    const long r  = i >> 7;
    const int  c  = (int)(i & 127);
    const long st = 8192L * 128;
    const long rb = r * 128;

    const int k = c & 63;
    float u = 0.f;
    if (k < 48) {
        const long o = rb + k;
        u = (Pout[o] + Pout[o + st]) + (Pout[o + 2 * st] + Pout[o + 3 * st]);
    }
    const __bf16 hi = (__bf16)u;
    xdtS[rb + c] = (c < 64) ? hi : (__bf16)(u - (float)hi);

    if (c >= 96) {                      // cols 96..127 also emit xbc 0..31
        const int j = c - 96;
        const long o = rb + 48 + j;
        xbc[r * 32 + j] =
            (Pout[o] + Pout[o + st]) + (Pout[o + 2 * st] + Pout[o + 3 * st]);
    }
}

// ---------------------------------------------------------------------------
// Merged input/weight split: x, W_in, W_out, W_x, W_dt (padded 1536x128).
// ---------------------------------------------------------------------------
#define NW0 ((long)BL * 768)
#define NW1 (3072L * 768)
#define NW2 (768L * 1536)
#define NW3 (80L * 1536)
#define NW4 (1536L * 128)
__global__ __launch_bounds__(256)
void split_all(const float* __restrict__ x,
               const float* __restrict__ W_in, const float* __restrict__ W_out,
               const float* __restrict__ W_x, const float* __restrict__ W_dt,
               __bf16* __restrict__ xS,
               __bf16* __restrict__ wInS, __bf16* __restrict__ wOutS,
               __bf16* __restrict__ wXS, __bf16* __restrict__ wDtS)
{
    long i = (long)blockIdx.x * 256 + threadIdx.x;
    if (i < NW0) {
        const long row = i / 768; const int col = (int)(i - row * 768);
        const float a = x[i];
        const __bf16 h = (__bf16)a;
        __bf16* d = xS + row * 1536 + col;
        d[0] = h; d[768] = (__bf16)(a - (float)h);
        return;
    }
    i -= NW0;
    if (i < NW1) {
        const long row = i / 768; const int col = (int)(i - row * 768);
        const float a = W_in[i];
        const __bf16 h = (__bf16)a;
        __bf16* d = wInS + row * 1536 + col;
        d[0] = h; d[768] = (__bf16)(a - (float)h);
        return;
    }
    i -= NW1;
    if (i < NW2) {
        const long row = i / 1536; const int col = (int)(i - row * 1536);
        const float a = W_out[i];
        const __bf16 h = (__bf16)a;
        __bf16* d = wOutS + row * 3072 + col;
        d[0] = h; d[1536] = (__bf16)(a - (float)h);
        return;
    }
    i -= NW2;
    if (i < NW3) {
        const long row = i / 1536; const int col = (int)(i - row * 1536);
        const float a = W_x[i];
        const __bf16 h = (__bf16)a;
        __bf16* d = wXS + row * 3072 + col;
        d[0] = h; d[1536] = (__bf16)(a - (float)h);
        return;
    }
    i -= NW3;
    if (i < NW4) {
        const long row = i >> 7; const int c = (int)(i & 127);
        const int k = c & 63;
        const float a = (k < 48) ? W_dt[row * 48 + k] : 0.f;
        const __bf16 h = (__bf16)a;
        wDtS[row * 128 + c] = (c < 64) ? h : (__bf16)(a - (float)h);
    }
}

// ---------------------------------------------------------------------------
// Depthwise causal conv (width 4) + bias + SiLU -> xcS split-bf16.
// R18: 4-wide vectorized (f32x4 taps/weights; 8B bf16 stores; 4x ILP).
// ---------------------------------------------------------------------------
typedef __bf16 bf16x4 __attribute__((ext_vector_type(4)));

__global__ __launch_bounds__(256)
void conv_silu_kernel(const float* __restrict__ xz,
                      const float* __restrict__ conv_w,
                      const float* __restrict__ conv_b,
                      __bf16* __restrict__ xcS)
{
    const long idx = (long)blockIdx.x * 256 + threadIdx.x;   // over BL*384
    const int d4 = (int)(idx % (D_INNER / 4)) * 4;           // 0,4,..,1532
    const long bl = idx / (D_INNER / 4);
    const int l  = (int)(bl % SEQ_LEN);

    // weights: conv_w[d][0..3] for 4 consecutive d -> 4 x f32x4 contiguous
    const f32x4 w0 = *(const f32x4*)&conv_w[(d4 + 0) * 4];
    const f32x4 w1 = *(const f32x4*)&conv_w[(d4 + 1) * 4];
    const f32x4 w2 = *(const f32x4*)&conv_w[(d4 + 2) * 4];
    const f32x4 w3 = *(const f32x4*)&conv_w[(d4 + 3) * 4];
    const f32x4 bb = *(const f32x4*)&conv_b[d4];

    const float* base = xz + bl * 3072 + d4;
    f32x4 t0 = {0.f,0.f,0.f,0.f}, t1 = t0, t2 = t0, t3;
    if (l >= 3) t0 = *(const f32x4*)(base - 3 * 3072);
    if (l >= 2) t1 = *(const f32x4*)(base - 2 * 3072);
    if (l >= 1) t2 = *(const f32x4*)(base - 1 * 3072);
    t3 = *(const f32x4*)base;

    bf16x4 hi4, lo4;
    #pragma unroll
    for (int e = 0; e < 4; ++e) {
        const f32x4 we = (e == 0) ? w0 : (e == 1) ? w1 : (e == 2) ? w2 : w3;
        float s = bb[e];
        s = fmaf(t0[e], we[0], s);
        s = fmaf(t1[e], we[1], s);
        s = fmaf(t2[e], we[2], s);
        s = fmaf(t3[e], we[3], s);
        const float sig = 1.f / (1.f + __expf(-s));
        const float v = s * sig;
        const __bf16 h = (__bf16)v;
        hi4[e] = h;
        lo4[e] = (__bf16)(v - (float)h);
    }
    *(bf16x4*)&xcS[bl * 3072 + d4]        = hi4;
    *(bf16x4*)&xcS[bl * 3072 + 1536 + d4] = lo4;
}

// ---------------------------------------------------------------------------
// Scan phase A: per (b, d, chunk): P = prod(a_l), S = local scan (h0=0).
// R18: unroll-4 l-loop + vectorized xbc loads (ILP for the serial chain).
// ---------------------------------------------------------------------------
__global__ __launch_bounds__(256)
void scan_phaseA(const __bf16* __restrict__ xcS, const float* __restrict__ xz,
                 const float* __restrict__ xbc, const float* __restrict__ A_log,
                 float* __restrict__ P, float* __restrict__ S)
{
    const int d = blockIdx.x * 256 + threadIdx.x;
    const int c = blockIdx.y;
    const int b = blockIdx.z;

    float An[16], Pr[16], Sr[16];
    #pragma unroll
    for (int n = 0; n < 16; ++n) {
        An[n] = -__expf(A_log[d * 16 + n]);
        Pr[n] = 1.f;
        Sr[n] = 0.f;
    }

    const long bl0 = (long)b * SEQ_LEN + (long)c * CHUNK;
    #pragma unroll 4
    for (int l = 0; l < CHUNK; ++l) {
        const long bl = bl0 + l;
        const float dt  = xz[bl * 3072 + d];
        const float x   = (float)xcS[bl * 3072 + d] + (float)xcS[bl * 3072 + 1536 + d];
        const float dtx = dt * x;
        float bcr[16];
        #pragma unroll
        for (int v = 0; v < 4; ++v)
            *(f32x4*)&bcr[v * 4] = *(const f32x4*)&xbc[bl * 32 + v * 4];
        #pragma unroll
        for (int n = 0; n < 16; ++n) {
            const float a = __expf(dt * An[n]);
            Pr[n] *= a;
            Sr[n] = fmaf(a, Sr[n], dtx * bcr[n]);
        }
    }

    const long base = ((long)(b * NCHUNK + c) * 16) * D_INNER + d;
    #pragma unroll
    for (int n = 0; n < 16; ++n) {
        P[base + (long)n * D_INNER] = Pr[n];
        S[base + (long)n * D_INNER] = Sr[n];
    }
}

// ---------------------------------------------------------------------------
// Scan phase B: one thread per (b, n, d) — 384 blocks, coalesced over d.
// ---------------------------------------------------------------------------
__global__ __launch_bounds__(256)
void scan_phaseB(const float* __restrict__ P, const float* __restrict__ S,
                 float* __restrict__ H)
{
    const int t = blockIdx.x * 256 + threadIdx.x;   // over BATCH*16*D_INNER
    const int d = t % D_INNER;
    const int r = t / D_INNER;
    const int n = r & 15;
    const int b = r >> 4;

    float h = 0.f;
    for (int c = 0; c < NCHUNK; ++c) {
        const long i = ((long)(b * NCHUNK + c) * 16 + n) * D_INNER + d;
        H[i] = h;
        h = fmaf(P[i], h, S[i]);
    }
}

// ---------------------------------------------------------------------------
// Scan phase C: re-run chunks from h_in, emit y, gate with silu(z), write
// split-bf16 in-place over xcS -> yS.
// R18: unroll-2 l-loop + vectorized xbc loads.
// ---------------------------------------------------------------------------
__global__ __launch_bounds__(256)
void scan_phaseC(__bf16* xcS_yS, const float* __restrict__ xz,
                 const float* __restrict__ xbc, const float* __restrict__ A_log,
                 const float* __restrict__ Dp, const float* __restrict__ H)
{
    const int d = blockIdx.x * 256 + threadIdx.x;
    const int c = blockIdx.y;
    const int b = blockIdx.z;

    float An[16], h[16];
    const long hbase = ((long)(b * NCHUNK + c) * 16) * D_INNER + d;
    #pragma unroll
    for (int n = 0; n < 16; ++n) {
        An[n] = -__expf(A_log[d * 16 + n]);
        h[n]  = H[hbase + (long)n * D_INNER];
    }
    const float Dd = Dp[d];

    const long bl0 = (long)b * SEQ_LEN + (long)c * CHUNK;
    #pragma unroll 2
    for (int l = 0; l < CHUNK; ++l) {
        const long bl = bl0 + l;
        const float dt  = xz[bl * 3072 + d];
        const float x   = (float)xcS_yS[bl * 3072 + d] + (float)xcS_yS[bl * 3072 + 1536 + d];
        const float dtx = dt * x;
        float bcr[32];
        #pragma unroll
        for (int v = 0; v < 8; ++v)
            *(f32x4*)&bcr[v * 4] = *(const f32x4*)&xbc[bl * 32 + v * 4];
        float y = Dd * x;
        #pragma unroll
        for (int n = 0; n < 16; ++n) {
            const float a = __expf(dt * An[n]);
            h[n] = fmaf(a, h[n], dtx * bcr[n]);
            y = fmaf(h[n], bcr[16 + n], y);
        }
        const float z  = xz[bl * 3072 + D_INNER + d];
        const float sz = z / (1.f + __expf(-z));
        const float v  = y * sz;
        const __bf16 hi = (__bf16)v;
        const __bf16 lo = (__bf16)(v - (float)hi);
        xcS_yS[bl * 3072 + d]        = hi;
        xcS_yS[bl * 3072 + 1536 + d] = lo;
    }
}

// ---------------------------------------------------------------------------
extern "C" void kernel_launch(void* const* d_in, const int* in_sizes, int n_in,
                              void* d_out, int out_size, void* d_ws, size_t ws_size,
                              hipStream_t stream)
{
    const float* x      = (const float*)d_in[0];   // (4,2048,768)
    const float* W_in   = (const float*)d_in[1];   // (3072,768)
    const float* conv_w = (const float*)d_in[2];   // (1536,1,4)
    const float* conv_b = (const float*)d_in[3];   // (1536,)
    const float* W_x    = (const float*)d_in[4];   // (80,1536)
    const float* W_dt   = (const float*)d_in[5];   // (1536,48)
    const float* b_dt   = (const float*)d_in[6];   // (1536,)
    const float* A_log  = (const float*)d_in[7];   // (1536,16)
    const float* D_p    = (const float*)d_in[8];   // (1536,)
    const float* W_out  = (const float*)d_in[9];   // (768,1536)
    float* out = (float*)d_out;                    // (4,2048,768)

    // ---- workspace carve, ~202 MB ---------------------------------------
    char* p = (char*)d_ws;
    auto take = [&](size_t bytes) { char* r = p; p += (bytes + 255) & ~(size_t)255; return r; };

    float*  xz    = (float*)take((size_t)BL * 3072 * 4);    // 100.7 MB (dt | z)
    float*  H     = (float*)take((size_t)BATCH * NCHUNK * 16 * D_INNER * 4); // 12.6 MB
    __bf16* wOutS = (__bf16*)take(768L * 3072 * 2);         //   4.7 MB
    __bf16* wXS   = (__bf16*)take(128L * 3072 * 2);         //   0.8 MB (80 valid)
    __bf16* wDtS  = (__bf16*)take(1536L * 128 * 2);         //   0.4 MB
    __bf16* xdtS  = (__bf16*)take(8192L * 128 * 2);         //   2.1 MB
    float*  xbc   = (float*)take(8192L * 32 * 4);           //   1.0 MB
    float*  Pout  = (float*)take(4L * 8192 * 128 * 4);      //  16.8 MB (-> P overlay)
    float*  S     = (float*)take((size_t)BATCH * NCHUNK * 16 * D_INNER * 4); // 12.6 MB
    float*  P     = Pout;   // Pout dead after xdbl_reduce3; P needs 12.6 MB

    // REGION (50.4 MB), time-multiplexed:
    //   phase 1:   xS (25.2MB) + wInS (9.4MB)
    //   phase 2-8: xcS (8192x3072 bf16), phaseC overwrites in-place -> yS
    char* region = take(50331648);
    __bf16* xS   = (__bf16*)region;
    __bf16* wInS = (__bf16*)(region + 25165824);
    __bf16* xcS  = (__bf16*)region;
    __bf16* yS   = (__bf16*)region;

    // 0) split conversions (x + weights, one launch)
    {
        const long n = NW0 + NW1 + NW2 + NW3 + NW4;
        split_all<<<(int)((n + 255) / 256), 256, 0, stream>>>(
            x, W_in, W_out, W_x, W_dt, xS, wInS, wOutS, wXS, wDtS);
    }
    // 1) xz = x @ W_in^T  (256x256 4-phase relaxed-vmcnt MFMA, K=768)
    {
        dim3 grid(3072 / 256, BL / 256);   // 12 x 32 = 384 blocks
        gemm256<<<grid, 512, 0, stream>>>(xS, wInS, xz, 768, 3072);
    }
    // 2) conv + bias + SiLU -> xcS (overlays xS), 4-wide
    {
        const long total = (long)BL * (D_INNER / 4);
        conv_silu_kernel<<<(int)(total / 256), 256, 0, stream>>>(xz, conv_w, conv_b, xcS);
    }
    // 3) x_dbl split-K MFMA -> Pout
    {
        dim3 grid(4, BL / 128);
        gemm_xdbl<<<grid, 256, 0, stream>>>(xcS, wXS, Pout);
    }
    // 4) reduce partials -> xbc + xdtS
    {
        const long n = 8192L * 128;
        xdbl_reduce3<<<(int)((n + 255) / 256), 256, 0, stream>>>(Pout, xbc, xdtS);
    }
    // 5) dt = softplus(xdt @ W_dt^T + b_dt)  (R10 MFMA, K=64 padded)
    {
        dim3 grid(1536 / 128, BL / 128);
        gemm_f<1><<<grid, 256, 0, stream>>>(xdtS, wDtS, xz, b_dt,
                                            BL, 1536, 64, 3072);
    }
    // 6) scan phase A  (P overlays dead Pout)
    {
        dim3 grid(D_INNER / 256, NCHUNK, BATCH);
        scan_phaseA<<<grid, 256, 0, stream>>>(xcS, xz, xbc, A_log, P, S);
    }
    // 7) scan phase B (per-(b,n,d): 384 blocks)
    scan_phaseB<<<(BATCH * 16 * D_INNER) / 256, 256, 0, stream>>>(P, S, H);
    // 8) scan phase C: xcS -> yS in-place
    {
        dim3 grid(D_INNER / 256, NCHUNK, BATCH);
        scan_phaseC<<<grid, 256, 0, stream>>>(xcS, xz, xbc, A_log, D_p, H);
    }
    // 9) out = y @ W_out^T  (R10 MFMA, M=8192, N=768, K=1536)
    {
        dim3 grid(768 / 128, BL / 128);
        gemm_f<0><<<grid, 256, 0, stream>>>(yS, wOutS, out, nullptr,
                                            BL, 768, 1536, 768);
    }
}

// Round 9
// 513.822 us; speedup vs baseline: 2.5441x; 1.0197x over previous
//
#include <hip/hip_runtime.h>
#include <hip/hip_bf16.h>
#include <math.h>

// Problem constants (fixed by reference)
#define D_MODEL   768
#define D_STATE   16
#define D_CONV    4
#define D_INNER   1536
#define DT_RANK   48
#define BATCH     4
#define SEQ_LEN   2048
#define BL        (BATCH * SEQ_LEN)        // 8192 rows
#define NCHUNK    32
#define CHUNK     (SEQ_LEN / NCHUNK)       // 64

typedef __bf16 bf16x8 __attribute__((ext_vector_type(8)));
typedef float  f32x4  __attribute__((ext_vector_type(4)));

__device__ __forceinline__ void async_copy16(const void* g, void* l) {
    __builtin_amdgcn_global_load_lds(
        (const __attribute__((address_space(1))) void*)g,
        (__attribute__((address_space(3))) void*)l,
        16, 0, 0);
}

// ===========================================================================
// Step-1 kernel: R15 verbatim (best verified: ~119 us, 41% MfmaUtil).
// 256x256 tile, 8 waves, 4-phase pipelined K-loop, relaxed counted vmcnt.
// ===========================================================================

#define SYNC_V6 do { asm volatile("s_waitcnt vmcnt(6)" ::: "memory"); \
    __builtin_amdgcn_s_barrier(); __builtin_amdgcn_sched_barrier(0); } while (0)
#define SYNC_V4 do { asm volatile("s_waitcnt vmcnt(4)" ::: "memory"); \
    __builtin_amdgcn_s_barrier(); __builtin_amdgcn_sched_barrier(0); } while (0)
#define SYNC_V2 do { asm volatile("s_waitcnt vmcnt(2)" ::: "memory"); \
    __builtin_amdgcn_s_barrier(); __builtin_amdgcn_sched_barrier(0); } while (0)
#define SYNC_V0 do { asm volatile("s_waitcnt vmcnt(0)" ::: "memory"); \
    __builtin_amdgcn_s_barrier(); __builtin_amdgcn_sched_barrier(0); } while (0)
#define SYNC_B  do { \
    __builtin_amdgcn_s_barrier(); __builtin_amdgcn_sched_barrier(0); } while (0)

template<int IH, int JH>
__device__ __forceinline__ void quad24(f32x4 (&acc)[2][4][2][2],
                                       const bf16x8 (&aH)[4], const bf16x8 (&aL)[4],
                                       const bf16x8 (&bH)[2], const bf16x8 (&bL)[2])
{
    __builtin_amdgcn_s_setprio(1);
    #pragma unroll
    for (int i = 0; i < 4; ++i)
        #pragma unroll
        for (int j = 0; j < 2; ++j) {
            acc[IH][i][JH][j] = __builtin_amdgcn_mfma_f32_16x16x32_bf16(aH[i], bH[j], acc[IH][i][JH][j], 0, 0, 0);
            acc[IH][i][JH][j] = __builtin_amdgcn_mfma_f32_16x16x32_bf16(aH[i], bL[j], acc[IH][i][JH][j], 0, 0, 0);
            acc[IH][i][JH][j] = __builtin_amdgcn_mfma_f32_16x16x32_bf16(aL[i], bH[j], acc[IH][i][JH][j], 0, 0, 0);
        }
    __builtin_amdgcn_s_setprio(0);
}

__global__ __launch_bounds__(512, 2)
void gemm256(const __bf16* __restrict__ A, const __bf16* __restrict__ B,
             float* __restrict__ C, int K, int ldc)
{
    __shared__ __bf16 Asl0[256 * 64];
    __shared__ __bf16 Bsl0[256 * 64];
    __shared__ __bf16 Asl1[256 * 64];
    __shared__ __bf16 Bsl1[256 * 64];

    const int tid  = threadIdx.x;
    const int lane = tid & 63;
    const int w    = tid >> 6;          // 0..7
    const int aw   = (w >> 2) * 64;     // A sub-slice within each 128-row half
    const int bw   = (w & 3) * 32;      // B sub-slice within each 128-row half

    const int bm = blockIdx.y * 256;
    const int bn = blockIdx.x * 256;

    const long lda = 2L * K;
    const long ldb = 2L * K;

    f32x4 acc[2][4][2][2];
    #pragma unroll
    for (int a = 0; a < 2; ++a)
        #pragma unroll
        for (int i = 0; i < 4; ++i)
            #pragma unroll
            for (int b = 0; b < 2; ++b)
                #pragma unroll
                for (int j = 0; j < 2; ++j)
                    acc[a][i][b][j] = (f32x4){0.f, 0.f, 0.f, 0.f};

    const int srow = w * 8 + (lane >> 3);
    const int q    = (lane & 7) ^ ((lane >> 3) & 7);
    const int qoff = (q < 4) ? q * 8 : K + (q - 4) * 8;
    const __bf16* Ab = A + (long)(bm + srow) * lda + qoff;
    const __bf16* Bb = B + (long)(bn + srow) * ldb + qoff;
    const long lda64 = 64 * lda, ldb64 = 64 * ldb;
    const int wo = w * 1024;            // wave's 8-row slice within a call

    const int fr = lane & 15;
    const int g4 = lane >> 4;           // k-chunk group 0..3 within 32-k tile

    const int nt = K >> 5;              // 32-k tiles, nt >= 2

    __bf16 *Ac = Asl0, *Bc = Bsl0, *An = Asl1, *Bn = Bsl1;

    auto stA = [&](int kk, __bf16* dst, int half) {
        char* d = (char*)dst + half * 16384 + wo;
        const __bf16* s = Ab + kk + (long)(2 * half) * lda64;
        async_copy16(s, d);
        async_copy16(s + lda64, d + 8192);
    };
    auto stB = [&](int kk, __bf16* dst, int half) {
        char* d = (char*)dst + half * 16384 + wo;
        const __bf16* s = Bb + kk + (long)(2 * half) * ldb64;
        async_copy16(s, d);
        async_copy16(s + ldb64, d + 8192);
    };
    auto rdA = [&](const __bf16* As, int ih, bf16x8 (&aH)[4], bf16x8 (&aL)[4]) {
        #pragma unroll
        for (int t = 0; t < 4; ++t) {
            const int ra = aw + ih * 128 + t * 16 + fr;
            aH[t] = *(const bf16x8*)&As[ra * 64 + ((g4       ^ (ra & 7)) * 8)];
            aL[t] = *(const bf16x8*)&As[ra * 64 + (((4 + g4) ^ (ra & 7)) * 8)];
        }
    };
    auto rdB = [&](const __bf16* Bs, int jh, bf16x8 (&bH)[2], bf16x8 (&bL)[2]) {
        #pragma unroll
        for (int t = 0; t < 2; ++t) {
            const int rb = bw + jh * 128 + t * 16 + fr;
            bH[t] = *(const bf16x8*)&Bs[rb * 64 + ((g4       ^ (rb & 7)) * 8)];
            bL[t] = *(const bf16x8*)&Bs[rb * 64 + (((4 + g4) ^ (rb & 7)) * 8)];
        }
    };

    // prologue: tile 0 units in consume order [A0, B0, B1, A1]
    stA(0, Ac, 0);
    stB(0, Bc, 0);
    stB(0, Bc, 1);
    stA(0, Ac, 1);
    SYNC_V4;

    for (int t = 0; t < nt - 1; ++t) {
        const int kk1 = (t + 1) * 32;
        bf16x8 aH[4], aL[4], bH[2], bL[2];
        // ph1 (0,0): reads A0,B0; stage A0(t+1)
        rdA(Ac, 0, aH, aL);
        rdB(Bc, 0, bH, bL);
        stA(kk1, An, 0);
        SYNC_V6;
        quad24<0, 0>(acc, aH, aL, bH, bL);
        // ph2 (0,1): reads B1; stage B0(t+1)
        rdB(Bc, 1, bH, bL);
        stB(kk1, Bn, 0);
        SYNC_V6;
        quad24<0, 1>(acc, aH, aL, bH, bL);
        // ph3 (1,1): reads A1; stage B1(t+1)
        rdA(Ac, 1, aH, aL);
        stB(kk1, Bn, 1);
        SYNC_V6;
        quad24<1, 1>(acc, aH, aL, bH, bL);
        // ph4 (1,0): re-reads B0; stage A1(t+1)
        rdB(Bc, 0, bH, bL);
        stA(kk1, An, 1);
        SYNC_B;
        quad24<1, 0>(acc, aH, aL, bH, bL);
        __bf16* tp;
        tp = Ac; Ac = An; An = tp;
        tp = Bc; Bc = Bn; Bn = tp;
    }

    // peeled last tile: drain 4 -> 2 -> 0
    {
        bf16x8 aH[4], aL[4], bH[2], bL[2];
        rdA(Ac, 0, aH, aL);
        rdB(Bc, 0, bH, bL);
        SYNC_V4;
        quad24<0, 0>(acc, aH, aL, bH, bL);
        rdB(Bc, 1, bH, bL);
        SYNC_V2;
        quad24<0, 1>(acc, aH, aL, bH, bL);
        rdA(Ac, 1, aH, aL);
        SYNC_V0;
        quad24<1, 1>(acc, aH, aL, bH, bL);
        rdB(Bc, 0, bH, bL);
        quad24<1, 0>(acc, aH, aL, bH, bL);
    }

    // C/D layout (m89-verified): col = lane&15, row = (lane>>4)*4 + reg
    const int cn  = lane & 15;
    const int cr4 = (lane >> 4) * 4;
    #pragma unroll
    for (int ih = 0; ih < 2; ++ih)
        #pragma unroll
        for (int i = 0; i < 4; ++i)
            #pragma unroll
            for (int jh = 0; jh < 2; ++jh)
                #pragma unroll
                for (int j = 0; j < 2; ++j)
                    #pragma unroll
                    for (int r = 0; r < 4; ++r) {
                        const int row = bm + aw + ih * 128 + i * 16 + cr4 + r;
                        const int col = bn + bw + jh * 128 + j * 16 + cn;
                        C[(long)row * ldc + col] = acc[ih][i][jh][j][r];
                    }
}

// ---------------------------------------------------------------------------
// Split-bf16 MFMA GEMM (NT), SINGLE-PASS K (R10 — known-good).  128x128 tile,
// 4 waves of 64x64.  EPI 0: plain store.  EPI 1: softplus(v + bias[col]).
// ---------------------------------------------------------------------------
template <int EPI>
__global__ __launch_bounds__(256)
void gemm_f(const __bf16* __restrict__ A, const __bf16* __restrict__ B,
            float* __restrict__ C, const float* __restrict__ bias,
            int M, int N, int K, int ldc)
{
    __shared__ __bf16 Asl[128 * 64];
    __shared__ __bf16 Bsl[128 * 64];

    const int tid  = threadIdx.x;
    const int lane = tid & 63;
    const int w    = tid >> 6;
    const int wm   = (w >> 1) * 64;
    const int wn   = (w & 1) * 64;

    const int bm = blockIdx.y * 128;
    const int bn = blockIdx.x * 128;

    const long lda = 2L * K;
    const long ldb = 2L * K;

    f32x4 acc[4][4];
    #pragma unroll
    for (int i = 0; i < 4; ++i)
        #pragma unroll
        for (int j = 0; j < 4; ++j)
            acc[i][j] = (f32x4){0.f, 0.f, 0.f, 0.f};

    const int srow = w * 32 + (lane >> 3);
    const int q    = (lane & 7) ^ ((lane >> 3) & 7);
    const int qoff = (q < 4) ? q * 8 : K + (q - 4) * 8;
    const __bf16* Abase = A + (long)(bm + srow) * lda + qoff;
    const __bf16* Bbase = B + (long)(bn + srow) * ldb + qoff;
    char* AslW = (char*)Asl + (w * 32) * 128;
    char* BslW = (char*)Bsl + (w * 32) * 128;

    const int fr = lane & 15;
    const int g4 = lane >> 4;          // k-chunk group 0..3 within 32-k tile
    const long lda8 = 8 * lda, ldb8 = 8 * ldb;

    for (int kk = 0; kk < K; kk += 32) {
        __syncthreads();
        #pragma unroll
        for (int j = 0; j < 4; ++j) {
            async_copy16(Abase + j * lda8 + kk, AslW + j * 1024);
            async_copy16(Bbase + j * ldb8 + kk, BslW + j * 1024);
        }
        __syncthreads();

        bf16x8 ah[4], al[4], bh[4], bl[4];
        #pragma unroll
        for (int t = 0; t < 4; ++t) {
            const int ra = wm + t * 16 + fr;
            const int rb = wn + t * 16 + fr;
            ah[t] = *(const bf16x8*)&Asl[ra * 64 + ((g4       ^ (ra & 7)) * 8)];
            al[t] = *(const bf16x8*)&Asl[ra * 64 + (((4 + g4) ^ (ra & 7)) * 8)];
            bh[t] = *(const bf16x8*)&Bsl[rb * 64 + ((g4       ^ (rb & 7)) * 8)];
            bl[t] = *(const bf16x8*)&Bsl[rb * 64 + (((4 + g4) ^ (rb & 7)) * 8)];
        }
        #pragma unroll
        for (int i = 0; i < 4; ++i)
            #pragma unroll
            for (int j = 0; j < 4; ++j) {
                acc[i][j] = __builtin_amdgcn_mfma_f32_16x16x32_bf16(ah[i], bh[j], acc[i][j], 0, 0, 0);
                acc[i][j] = __builtin_amdgcn_mfma_f32_16x16x32_bf16(ah[i], bl[j], acc[i][j], 0, 0, 0);
                acc[i][j] = __builtin_amdgcn_mfma_f32_16x16x32_bf16(al[i], bh[j], acc[i][j], 0, 0, 0);
            }
    }

    // C/D layout (m89-verified): col = lane&15, row = (lane>>4)*4 + reg
    const int cn  = lane & 15;
    const int cr4 = (lane >> 4) * 4;
    #pragma unroll
    for (int i = 0; i < 4; ++i)
        #pragma unroll
        for (int j = 0; j < 4; ++j)
            #pragma unroll
            for (int r = 0; r < 4; ++r) {
                const int row = bm + wm + i * 16 + cr4 + r;
                const int col = bn + wn + j * 16 + cn;
                float v = acc[i][j][r];
                if (EPI == 1) {
                    v += bias[col];
                    v = fmaxf(v, 0.f) + log1pf(__expf(-fabsf(v)));  // stable softplus
                }
                C[(long)row * ldc + col] = v;
            }
}

// ---------------------------------------------------------------------------
// x_dbl split-K MFMA GEMM (R19): identical main loop to R10, but the
// epilogue ATOMICALLY accumulates the 4 split-K partials directly into
// xdtP (8192x48 f32, cols 0..47) and xbc (8192x32 f32, cols 48..79),
// eliminating the 16.8 MB Pout round-trip and the 67-MB-read reduce kernel.
// Cols 80..127 (zero/garbage-padded B rows) are skipped — MFMA output is
// column-independent, so the padding never contaminates valid columns.
// xbc/xdtP must be zeroed before this kernel (zero_xp).
// ---------------------------------------------------------------------------
__global__ __launch_bounds__(256)
void gemm_xdbl(const __bf16* __restrict__ A, const __bf16* __restrict__ B,
               float* __restrict__ xdtP, float* __restrict__ xbc)
{
    __shared__ __bf16 Asl[128 * 64];
    __shared__ __bf16 Bsl[128 * 64];

    const int tid  = threadIdx.x;
    const int lane = tid & 63;
    const int w    = tid >> 6;
    const int wm   = (w >> 1) * 64;
    const int wn   = (w & 1) * 64;

    const int s  = blockIdx.x;           // split-K index 0..3
    const int bm = blockIdx.y * 128;
    const int K  = 1536;
    const long lda = 3072, ldb = 3072;

    f32x4 acc[4][4];
    #pragma unroll
    for (int i = 0; i < 4; ++i)
        #pragma unroll
        for (int j = 0; j < 4; ++j)
            acc[i][j] = (f32x4){0.f, 0.f, 0.f, 0.f};

    const int srow = w * 32 + (lane >> 3);
    const int q    = (lane & 7) ^ ((lane >> 3) & 7);
    const int qoff = (q < 4) ? q * 8 : K + (q - 4) * 8;
    const __bf16* Abase = A + (long)(bm + srow) * lda + qoff;
    const __bf16* Bbase = B + (long)srow * ldb + qoff;
    char* AslW = (char*)Asl + (w * 32) * 128;
    char* BslW = (char*)Bsl + (w * 32) * 128;

    const int fr = lane & 15;
    const int g4 = lane >> 4;
    const long lda8 = 8 * lda, ldb8 = 8 * ldb;

    for (int kt = s * 12; kt < (s + 1) * 12; ++kt) {
        const int kk = kt * 32;
        __syncthreads();
        #pragma unroll
        for (int j = 0; j < 4; ++j) {
            async_copy16(Abase + j * lda8 + kk, AslW + j * 1024);
            async_copy16(Bbase + j * ldb8 + kk, BslW + j * 1024);
        }
        __syncthreads();

        bf16x8 ah[4], al[4], bh[4], bl[4];
        #pragma unroll
        for (int t = 0; t < 4; ++t) {
            const int ra = wm + t * 16 + fr;
            const int rb = wn + t * 16 + fr;
            ah[t] = *(const bf16x8*)&Asl[ra * 64 + ((g4       ^ (ra & 7)) * 8)];
            al[t] = *(const bf16x8*)&Asl[ra * 64 + (((4 + g4) ^ (ra & 7)) * 8)];
            bh[t] = *(const bf16x8*)&Bsl[rb * 64 + ((g4       ^ (rb & 7)) * 8)];
            bl[t] = *(const bf16x8*)&Bsl[rb * 64 + (((4 + g4) ^ (rb & 7)) * 8)];
        }
        #pragma unroll
        for (int i = 0; i < 4; ++i)
            #pragma unroll
            for (int j = 0; j < 4; ++j) {
                acc[i][j] = __builtin_amdgcn_mfma_f32_16x16x32_bf16(ah[i], bh[j], acc[i][j], 0, 0, 0);
                acc[i][j] = __builtin_amdgcn_mfma_f32_16x16x32_bf16(ah[i], bl[j], acc[i][j], 0, 0, 0);
                acc[i][j] = __builtin_amdgcn_mfma_f32_16x16x32_bf16(al[i], bh[j], acc[i][j], 0, 0, 0);
            }
    }

    // atomic split-K merge epilogue (branches wave-uniform per (wn,j))
    const int cn  = lane & 15;
    const int cr4 = (lane >> 4) * 4;
    #pragma unroll
    for (int i = 0; i < 4; ++i)
        #pragma unroll
        for (int j = 0; j < 4; ++j) {
            const int col = wn + j * 16 + cn;
            if (col >= 80) continue;
            #pragma unroll
            for (int r = 0; r < 4; ++r) {
                const int row = bm + wm + i * 16 + cr4 + r;
                const float v = acc[i][j][r];
                if (col < 48) atomicAdd(&xdtP[(long)row * 48 + col], v);
                else          atomicAdd(&xbc [(long)row * 32 + (col - 48)], v);
            }
        }
}

// ---------------------------------------------------------------------------
// Zero xbc (8192x32) and xdtP (8192x48) before atomic accumulation.
// ---------------------------------------------------------------------------
__global__ __launch_bounds__(256)
void zero_xp(float* __restrict__ xbc, float* __restrict__ xdtP)
{
    const long i = (long)blockIdx.x * 256 + threadIdx.x;
    if (i < 8192L * 32) xbc[i]  = 0.f;
    if (i < 8192L * 48) xdtP[i] = 0.f;
}

// ---------------------------------------------------------------------------
// xdtP (f32) -> xdtS (8192 x 128 padded split-bf16: hi of k 0..47 at cols
// 0..47, lo at 64..111, zero pads) — the dt-GEMM A operand.
// ---------------------------------------------------------------------------
__global__ __launch_bounds__(256)
void xdt_split(const float* __restrict__ xdtP, __bf16* __restrict__ xdtS)
{
    const long i = (long)blockIdx.x * 256 + threadIdx.x;   // over 8192*128
    if (i >= 8192L * 128) return;
    const long r = i >> 7;
    const int  c = (int)(i & 127);
    const int  k = c & 63;
    const float u = (k < 48) ? xdtP[r * 48 + k] : 0.f;
    const __bf16 hi = (__bf16)u;
    xdtS[i] = (c < 64) ? hi : (__bf16)(u - (float)hi);
}

// ---------------------------------------------------------------------------
// Merged input/weight split: x, W_in, W_out, W_x, W_dt (padded 1536x128).
// ---------------------------------------------------------------------------
#define NW0 ((long)BL * 768)
#define NW1 (3072L * 768)
#define NW2 (768L * 1536)
#define NW3 (80L * 1536)
#define NW4 (1536L * 128)
__global__ __launch_bounds__(256)
void split_all(const float* __restrict__ x,
               const float* __restrict__ W_in, const float* __restrict__ W_out,
               const float* __restrict__ W_x, const float* __restrict__ W_dt,
               __bf16* __restrict__ xS,
               __bf16* __restrict__ wInS, __bf16* __restrict__ wOutS,
               __bf16* __restrict__ wXS, __bf16* __restrict__ wDtS)
{
    long i = (long)blockIdx.x * 256 + threadIdx.x;
    if (i < NW0) {
        const long row = i / 768; const int col = (int)(i - row * 768);
        const float a = x[i];
        const __bf16 h = (__bf16)a;
        __bf16* d = xS + row * 1536 + col;
        d[0] = h; d[768] = (__bf16)(a - (float)h);
        return;
    }
    i -= NW0;
    if (i < NW1) {
        const long row = i / 768; const int col = (int)(i - row * 768);
        const float a = W_in[i];
        const __bf16 h = (__bf16)a;
        __bf16* d = wInS + row * 1536 + col;
        d[0] = h; d[768] = (__bf16)(a - (float)h);
        return;
    }
    i -= NW1;
    if (i < NW2) {
        const long row = i / 1536; const int col = (int)(i - row * 1536);
        const float a = W_out[i];
        const __bf16 h = (__bf16)a;
        __bf16* d = wOutS + row * 3072 + col;
        d[0] = h; d[1536] = (__bf16)(a - (float)h);
        return;
    }
    i -= NW2;
    if (i < NW3) {
        const long row = i / 1536; const int col = (int)(i - row * 1536);
        const float a = W_x[i];
        const __bf16 h = (__bf16)a;
        __bf16* d = wXS + row * 3072 + col;
        d[0] = h; d[1536] = (__bf16)(a - (float)h);
        return;
    }
    i -= NW3;
    if (i < NW4) {
        const long row = i >> 7; const int c = (int)(i & 127);
        const int k = c & 63;
        const float a = (k < 48) ? W_dt[row * 48 + k] : 0.f;
        const __bf16 h = (__bf16)a;
        wDtS[row * 128 + c] = (c < 64) ? h : (__bf16)(a - (float)h);
    }
}

// ---------------------------------------------------------------------------
// Depthwise causal conv (width 4) + bias + SiLU -> xcS split-bf16.
// 4-wide vectorized (f32x4 taps/weights; 8B bf16 stores; 4x ILP).
// ---------------------------------------------------------------------------
typedef __bf16 bf16x4 __attribute__((ext_vector_type(4)));

__global__ __launch_bounds__(256)
void conv_silu_kernel(const float* __restrict__ xz,
                      const float* __restrict__ conv_w,
                      const float* __restrict__ conv_b,
                      __bf16* __restrict__ xcS)
{
    const long idx = (long)blockIdx.x * 256 + threadIdx.x;   // over BL*384
    const int d4 = (int)(idx % (D_INNER / 4)) * 4;           // 0,4,..,1532
    const long bl = idx / (D_INNER / 4);
    const int l  = (int)(bl % SEQ_LEN);

    const f32x4 w0 = *(const f32x4*)&conv_w[(d4 + 0) * 4];
    const f32x4 w1 = *(const f32x4*)&conv_w[(d4 + 1) * 4];
    const f32x4 w2 = *(const f32x4*)&conv_w[(d4 + 2) * 4];
    const f32x4 w3 = *(const f32x4*)&conv_w[(d4 + 3) * 4];
    const f32x4 bb = *(const f32x4*)&conv_b[d4];

    const float* base = xz + bl * 3072 + d4;
    f32x4 t0 = {0.f,0.f,0.f,0.f}, t1 = t0, t2 = t0, t3;
    if (l >= 3) t0 = *(const f32x4*)(base - 3 * 3072);
    if (l >= 2) t1 = *(const f32x4*)(base - 2 * 3072);
    if (l >= 1) t2 = *(const f32x4*)(base - 1 * 3072);
    t3 = *(const f32x4*)base;

    bf16x4 hi4, lo4;
    #pragma unroll
    for (int e = 0; e < 4; ++e) {
        const f32x4 we = (e == 0) ? w0 : (e == 1) ? w1 : (e == 2) ? w2 : w3;
        float s = bb[e];
        s = fmaf(t0[e], we[0], s);
        s = fmaf(t1[e], we[1], s);
        s = fmaf(t2[e], we[2], s);
        s = fmaf(t3[e], we[3], s);
        const float sig = 1.f / (1.f + __expf(-s));
        const float v = s * sig;
        const __bf16 h = (__bf16)v;
        hi4[e] = h;
        lo4[e] = (__bf16)(v - (float)h);
    }
    *(bf16x4*)&xcS[bl * 3072 + d4]        = hi4;
    *(bf16x4*)&xcS[bl * 3072 + 1536 + d4] = lo4;
}

// ---------------------------------------------------------------------------
// Scan phase A: per (b, d, chunk): P = prod(a_l), S = local scan (h0=0).
// ---------------------------------------------------------------------------
__global__ __launch_bounds__(256)
void scan_phaseA(const __bf16* __restrict__ xcS, const float* __restrict__ xz,
                 const float* __restrict__ xbc, const float* __restrict__ A_log,
                 float* __restrict__ P, float* __restrict__ S)
{
    const int d = blockIdx.x * 256 + threadIdx.x;
    const int c = blockIdx.y;
    const int b = blockIdx.z;

    float An[16], Pr[16], Sr[16];
    #pragma unroll
    for (int n = 0; n < 16; ++n) {
        An[n] = -__expf(A_log[d * 16 + n]);
        Pr[n] = 1.f;
        Sr[n] = 0.f;
    }

    const long bl0 = (long)b * SEQ_LEN + (long)c * CHUNK;
    #pragma unroll 4
    for (int l = 0; l < CHUNK; ++l) {
        const long bl = bl0 + l;
        const float dt  = xz[bl * 3072 + d];
        const float x   = (float)xcS[bl * 3072 + d] + (float)xcS[bl * 3072 + 1536 + d];
        const float dtx = dt * x;
        float bcr[16];
        #pragma unroll
        for (int v = 0; v < 4; ++v)
            *(f32x4*)&bcr[v * 4] = *(const f32x4*)&xbc[bl * 32 + v * 4];
        #pragma unroll
        for (int n = 0; n < 16; ++n) {
            const float a = __expf(dt * An[n]);
            Pr[n] *= a;
            Sr[n] = fmaf(a, Sr[n], dtx * bcr[n]);
        }
    }

    const long base = ((long)(b * NCHUNK + c) * 16) * D_INNER + d;
    #pragma unroll
    for (int n = 0; n < 16; ++n) {
        P[base + (long)n * D_INNER] = Pr[n];
        S[base + (long)n * D_INNER] = Sr[n];
    }
}

// ---------------------------------------------------------------------------
// Scan phase B: one thread per (b, n, d) — 384 blocks, coalesced over d.
// ---------------------------------------------------------------------------
__global__ __launch_bounds__(256)
void scan_phaseB(const float* __restrict__ P, const float* __restrict__ S,
                 float* __restrict__ H)
{
    const int t = blockIdx.x * 256 + threadIdx.x;   // over BATCH*16*D_INNER
    const int d = t % D_INNER;
    const int r = t / D_INNER;
    const int n = r & 15;
    const int b = r >> 4;

    float h = 0.f;
    for (int c = 0; c < NCHUNK; ++c) {
        const long i = ((long)(b * NCHUNK + c) * 16 + n) * D_INNER + d;
        H[i] = h;
        h = fmaf(P[i], h, S[i]);
    }
}

// ---------------------------------------------------------------------------
// Scan phase C: re-run chunks from h_in, emit y, gate with silu(z), write
// split-bf16 in-place over xcS -> yS.
// ---------------------------------------------------------------------------
__global__ __launch_bounds__(256)
void scan_phaseC(__bf16* xcS_yS, const float* __restrict__ xz,
                 const float* __restrict__ xbc, const float* __restrict__ A_log,
                 const float* __restrict__ Dp, const float* __restrict__ H)
{
    const int d = blockIdx.x * 256 + threadIdx.x;
    const int c = blockIdx.y;
    const int b = blockIdx.z;

    float An[16], h[16];
    const long hbase = ((long)(b * NCHUNK + c) * 16) * D_INNER + d;
    #pragma unroll
    for (int n = 0; n < 16; ++n) {
        An[n] = -__expf(A_log[d * 16 + n]);
        h[n]  = H[hbase + (long)n * D_INNER];
    }
    const float Dd = Dp[d];

    const long bl0 = (long)b * SEQ_LEN + (long)c * CHUNK;
    #pragma unroll 2
    for (int l = 0; l < CHUNK; ++l) {
        const long bl = bl0 + l;
        const float dt  = xz[bl * 3072 + d];
        const float x   = (float)xcS_yS[bl * 3072 + d] + (float)xcS_yS[bl * 3072 + 1536 + d];
        const float dtx = dt * x;
        float bcr[32];
        #pragma unroll
        for (int v = 0; v < 8; ++v)
            *(f32x4*)&bcr[v * 4] = *(const f32x4*)&xbc[bl * 32 + v * 4];
        float y = Dd * x;
        #pragma unroll
        for (int n = 0; n < 16; ++n) {
            const float a = __expf(dt * An[n]);
            h[n] = fmaf(a, h[n], dtx * bcr[n]);
            y = fmaf(h[n], bcr[16 + n], y);
        }
        const float z  = xz[bl * 3072 + D_INNER + d];
        const float sz = z / (1.f + __expf(-z));
        const float v  = y * sz;
        const __bf16 hi = (__bf16)v;
        const __bf16 lo = (__bf16)(v - (float)hi);
        xcS_yS[bl * 3072 + d]        = hi;
        xcS_yS[bl * 3072 + 1536 + d] = lo;
    }
}

// ---------------------------------------------------------------------------
extern "C" void kernel_launch(void* const* d_in, const int* in_sizes, int n_in,
                              void* d_out, int out_size, void* d_ws, size_t ws_size,
                              hipStream_t stream)
{
    const float* x      = (const float*)d_in[0];   // (4,2048,768)
    const float* W_in   = (const float*)d_in[1];   // (3072,768)
    const float* conv_w = (const float*)d_in[2];   // (1536,1,4)
    const float* conv_b = (const float*)d_in[3];   // (1536,)
    const float* W_x    = (const float*)d_in[4];   // (80,1536)
    const float* W_dt   = (const float*)d_in[5];   // (1536,48)
    const float* b_dt   = (const float*)d_in[6];   // (1536,)
    const float* A_log  = (const float*)d_in[7];   // (1536,16)
    const float* D_p    = (const float*)d_in[8];   // (1536,)
    const float* W_out  = (const float*)d_in[9];   // (768,1536)
    float* out = (float*)d_out;                    // (4,2048,768)

    // ---- workspace carve, ~204 MB ---------------------------------------
    char* p = (char*)d_ws;
    auto take = [&](size_t bytes) { char* r = p; p += (bytes + 255) & ~(size_t)255; return r; };

    float*  xz    = (float*)take((size_t)BL * 3072 * 4);    // 100.7 MB (dt | z)
    float*  H     = (float*)take((size_t)BATCH * NCHUNK * 16 * D_INNER * 4); // 12.6 MB
    __bf16* wOutS = (__bf16*)take(768L * 3072 * 2);         //   4.7 MB
    __bf16* wXS   = (__bf16*)take(128L * 3072 * 2);         //   0.8 MB (80 valid)
    __bf16* wDtS  = (__bf16*)take(1536L * 128 * 2);         //   0.4 MB
    __bf16* xdtS  = (__bf16*)take(8192L * 128 * 2);         //   2.1 MB
    float*  xdtP  = (float*)take(8192L * 48 * 4);           //   1.6 MB
    float*  xbc   = (float*)take(8192L * 32 * 4);           //   1.0 MB
    float*  Pout  = (float*)take(4L * 8192 * 128 * 4);      //  16.8 MB (P overlay)
    float*  S     = (float*)take((size_t)BATCH * NCHUNK * 16 * D_INNER * 4); // 12.6 MB
    float*  P     = Pout;   // P (phaseA) overlays the former Pout region

    // REGION (50.4 MB), time-multiplexed:
    //   phase 1:   xS (25.2MB) + wInS (9.4MB)
    //   phase 2-8: xcS (8192x3072 bf16), phaseC overwrites in-place -> yS
    char* region = take(50331648);
    __bf16* xS   = (__bf16*)region;
    __bf16* wInS = (__bf16*)(region + 25165824);
    __bf16* xcS  = (__bf16*)region;
    __bf16* yS   = (__bf16*)region;

    // 0) split conversions (x + weights, one launch)
    {
        const long n = NW0 + NW1 + NW2 + NW3 + NW4;
        split_all<<<(int)((n + 255) / 256), 256, 0, stream>>>(
            x, W_in, W_out, W_x, W_dt, xS, wInS, wOutS, wXS, wDtS);
    }
    // 1) xz = x @ W_in^T  (256x256 4-phase relaxed-vmcnt MFMA, K=768)
    {
        dim3 grid(3072 / 256, BL / 256);   // 12 x 32 = 384 blocks
        gemm256<<<grid, 512, 0, stream>>>(xS, wInS, xz, 768, 3072);
    }
    // 2) conv + bias + SiLU -> xcS (overlays xS), 4-wide
    {
        const long total = (long)BL * (D_INNER / 4);
        conv_silu_kernel<<<(int)(total / 256), 256, 0, stream>>>(xz, conv_w, conv_b, xcS);
    }
    // 3a) zero atomic accumulators
    zero_xp<<<(int)((8192L * 48 + 255) / 256), 256, 0, stream>>>(xbc, xdtP);
    // 3b) x_dbl split-K MFMA with atomic merge -> xdtP + xbc
    {
        dim3 grid(4, BL / 128);
        gemm_xdbl<<<grid, 256, 0, stream>>>(xcS, wXS, xdtP, xbc);
    }
    // 4) xdtP -> xdtS (split-bf16 padded operand)
    {
        const long n = 8192L * 128;
        xdt_split<<<(int)((n + 255) / 256), 256, 0, stream>>>(xdtP, xdtS);
    }
    // 5) dt = softplus(xdt @ W_dt^T + b_dt)  (R10 MFMA, K=64 padded)
    {
        dim3 grid(1536 / 128, BL / 128);
        gemm_f<1><<<grid, 256, 0, stream>>>(xdtS, wDtS, xz, b_dt,
                                            BL, 1536, 64, 3072);
    }
    // 6) scan phase A  (P overlays the former Pout region)
    {
        dim3 grid(D_INNER / 256, NCHUNK, BATCH);
        scan_phaseA<<<grid, 256, 0, stream>>>(xcS, xz, xbc, A_log, P, S);
    }
    // 7) scan phase B (per-(b,n,d): 384 blocks)
    scan_phaseB<<<(BATCH * 16 * D_INNER) / 256, 256, 0, stream>>>(P, S, H);
    // 8) scan phase C: xcS -> yS in-place
    {
        dim3 grid(D_INNER / 256, NCHUNK, BATCH);
        scan_phaseC<<<grid, 256, 0, stream>>>(xcS, xz, xbc, A_log, D_p, H);
    }
    // 9) out = y @ W_out^T  (R10 MFMA, M=8192, N=768, K=1536)
    {
        dim3 grid(768 / 128, BL / 128);
        gemm_f<0><<<grid, 256, 0, stream>>>(yS, wOutS, out, nullptr,
                                            BL, 768, 1536, 768);
    }
}